// Round 7
// baseline (1614.445 us; speedup 1.0000x reference)
//
#include <hip/hip_runtime.h>
#include <hip/hip_fp16.h>
#include <math.h>

#define Nn 50000
#define Ff 16
#define Tt 12
#define Hh 64
#define Ee 1600000
#define Cc 80  // F + H

#define SCAN_NB 98  // ceil(50000 / 512)

typedef _Float16 f16x8 __attribute__((ext_vector_type(8)));
typedef float f32x4 __attribute__((ext_vector_type(4)));

static __device__ __forceinline__ float sigmoidf_(float x) { return 1.0f / (1.0f + expf(-x)); }

// ---------------- CSR build ----------------
__global__ void k_deg(const int* __restrict__ ei, const float* __restrict__ ew,
                      unsigned long long* __restrict__ dc) {
  int e = blockIdx.x * blockDim.x + threadIdx.x;
  if (e >= Ee) return;
  int d = ei[Ee + e];
  unsigned long long pk = (1ULL << 42) + (unsigned long long)(ew[e] * 2097152.0f + 0.5f);
  atomicAdd(&dc[d], pk);
}

__global__ void k_dis(const unsigned long long* __restrict__ dc,
                      float* __restrict__ dis, int* __restrict__ cnt) {
  int i = blockIdx.x * blockDim.x + threadIdx.x;
  if (i >= Nn) return;
  unsigned long long v = dc[i];
  cnt[i] = (int)(v >> 42);
  float deg = (float)(v & ((1ULL << 42) - 1)) * (1.0f / 2097152.0f);
  dis[i] = 1.0f / sqrtf(deg + 1.0f);
}

// ---- multi-block exclusive scan of cnt[Nn] -> rp/cur ----
__global__ __launch_bounds__(256) void k_scan1(const int* __restrict__ cnt,
                                               int* __restrict__ bsum) {
  __shared__ int ss[256];
  int b = blockIdx.x, t = threadIdx.x;
  int base = b * 512 + t * 2;
  int s = 0;
  if (base < Nn) s += cnt[base];
  if (base + 1 < Nn) s += cnt[base + 1];
  ss[t] = s;
  __syncthreads();
  for (int off = 128; off > 0; off >>= 1) {
    if (t < off) ss[t] += ss[t + off];
    __syncthreads();
  }
  if (t == 0) bsum[b] = ss[0];
}

__global__ __launch_bounds__(128) void k_scan2(const int* __restrict__ bsum,
                                               int* __restrict__ boff) {
  __shared__ int ss[128];
  int t = threadIdx.x;
  int v = (t < SCAN_NB) ? bsum[t] : 0;
  ss[t] = v;
  __syncthreads();
  for (int off = 1; off < 128; off <<= 1) {
    int u = (t >= off) ? ss[t - off] : 0;
    __syncthreads();
    ss[t] += u;
    __syncthreads();
  }
  if (t < SCAN_NB) boff[t] = ss[t] - v;  // exclusive
}

__global__ __launch_bounds__(256) void k_scan3(const int* __restrict__ cnt,
                                               const int* __restrict__ boff,
                                               int* __restrict__ rp, int* __restrict__ cur) {
  __shared__ int ss[256];
  int b = blockIdx.x, t = threadIdx.x;
  int base = b * 512 + t * 2;
  int c0 = (base < Nn) ? cnt[base] : 0;
  int c1 = (base + 1 < Nn) ? cnt[base + 1] : 0;
  int s = c0 + c1;
  ss[t] = s;
  __syncthreads();
  for (int off = 1; off < 256; off <<= 1) {
    int u = (t >= off) ? ss[t - off] : 0;
    __syncthreads();
    ss[t] += u;
    __syncthreads();
  }
  int run = boff[b] + ss[t] - s;
  if (base < Nn) { rp[base] = run; cur[base] = run; }
  if (base + 1 < Nn) { rp[base + 1] = run + c0; cur[base + 1] = run + c0; }
  if (b == 0 && t == 0) rp[Nn] = Ee;
}

// edge2[pos] = {src, normalized fp32 weight}: ONE scattered 8-B store per edge
__global__ void k_scatter(const int* __restrict__ ei, const float* __restrict__ ew,
                          const float* __restrict__ dis, int* __restrict__ cur,
                          int2* __restrict__ edge2) {
  int e = blockIdx.x * blockDim.x + threadIdx.x;
  if (e >= Ee) return;
  int s = ei[e];
  int d = ei[Ee + e];
  float w = ew[e] * dis[s] * dis[d];
  int pos = atomicAdd(&cur[d], 1);
  edge2[pos] = make_int2(s, __float_as_int(w));
}

// edge4[e] = u16 src | fp16 w << 16 (sequential read/write; no second scatter stream)
__global__ void k_pack(const int2* __restrict__ edge2, unsigned* __restrict__ edge4) {
  int e = blockIdx.x * blockDim.x + threadIdx.x;
  if (e >= Ee) return;
  int2 v = edge2[e];
  __half wh = __float2half(__int_as_float(v.y));
  edge4[e] = (unsigned)(v.x & 0xFFFF) | ((unsigned)__half_as_ushort(wh) << 16);
}

// ---------------- x fp32 -> fp16 (once) ----------------
__global__ void k_cvt_x(const float* __restrict__ x, __half* __restrict__ x16) {
  size_t idx = (size_t)blockIdx.x * blockDim.x + threadIdx.x;
  const size_t total = (size_t)Nn * Ff * Tt;
  if (idx < total) x16[idx] = __float2half(x[idx]);
}

// ---------------- weight fragments for MFMA (once) ----------------
__global__ void k_wfrag(const float* __restrict__ Wz, const float* __restrict__ Wr,
                        const float* __restrict__ Wh, __half* __restrict__ frag) {
  int t = blockIdx.x * 256 + threadIdx.x;
  if (t >= 12 * 3 * 64) return;
  int s = t / 192, rem = t % 192, ks = rem / 64, lane = rem % 64;
  int q = lane >> 4, nl = lane & 15;
  const float* W = (s < 4) ? Wz : (s < 8) ? Wr : Wh;
  int n0 = (s & 3) * 16;
  __half tmp[8];
#pragma unroll
  for (int j = 0; j < 8; j++) {
    int k = ks * 32 + q * 8 + j;
    float v = (k < Cc) ? W[k * Hh + n0 + nl] : 0.f;
    tmp[j] = __float2half(v);
  }
  *(uint4*)(frag + ((size_t)(s * 3 + ks) * 64 + lane) * 8) = *(uint4*)tmp;
}

__global__ void k_wfrag_a(const float* __restrict__ Wa, __half* __restrict__ fragA) {
  int t = blockIdx.x * 256 + threadIdx.x;
  if (t >= 8 * 64) return;
  int s = t >> 6, lane = t & 63;
  int tile = s >> 1, ks = s & 1;
  int q = lane >> 4, m = lane & 15;
  __half tmp[8];
#pragma unroll
  for (int j = 0; j < 8; j++) {
    int k = ks * 32 + q * 8 + j;
    tmp[j] = __float2half(Wa[k * Hh + tile * 16 + m]);
  }
  *(uint4*)(fragA + ((size_t)t) * 8) = *(uint4*)tmp;
}

// ---------------- Px16[t][i][f] = (A_hat @ x): wave per node, 48 lanes x 8B per edge ----------------
__global__ __launch_bounds__(256) void k_agg_px(
    const float* __restrict__ x, const __half* __restrict__ x16, __half* __restrict__ Px16,
    const int* __restrict__ rp, const int2* __restrict__ edge2,
    const float* __restrict__ dis) {
  int i = blockIdx.x * 4 + (threadIdx.x >> 6);
  if (i >= Nn) return;
  int lane = threadIdx.x & 63;
  const int R = Ff * Tt;  // 192
  const bool act = lane < 48;
  float d = dis[i], sn = d * d;
  float a0 = 0.f, a1 = 0.f, a2 = 0.f, a3 = 0.f;
  if (act) {
    float4 sv = *(const float4*)(x + (size_t)i * R + 4 * lane);  // self, fp32 exact
    a0 = sn * sv.x; a1 = sn * sv.y; a2 = sn * sv.z; a3 = sn * sv.w;
  }
  int jb = rp[i], je = rp[i + 1];
  for (int j = jb; j < je; j += 2) {
    int jc1 = min(j + 1, Ee - 1);
    int2 e0 = edge2[j];
    int2 e1 = edge2[jc1];
    float w0 = __int_as_float(e0.y);
    float w1 = (j + 1 < je) ? __int_as_float(e1.y) : 0.f;
    if (act) {
      uint2 g0 = *(const uint2*)(x16 + (size_t)e0.x * R + 4 * lane);
      uint2 g1 = *(const uint2*)(x16 + (size_t)e1.x * R + 4 * lane);
      float2 p01 = __half22float2(*reinterpret_cast<const __half2*>(&g0.x));
      float2 p23 = __half22float2(*reinterpret_cast<const __half2*>(&g0.y));
      float2 q01 = __half22float2(*reinterpret_cast<const __half2*>(&g1.x));
      float2 q23 = __half22float2(*reinterpret_cast<const __half2*>(&g1.y));
      a0 = fmaf(w0, p01.x, a0); a1 = fmaf(w0, p01.y, a1);
      a2 = fmaf(w0, p23.x, a2); a3 = fmaf(w0, p23.y, a3);
      a0 = fmaf(w1, q01.x, a0); a1 = fmaf(w1, q01.y, a1);
      a2 = fmaf(w1, q23.x, a2); a3 = fmaf(w1, q23.y, a3);
    }
  }
  if (act) {
#pragma unroll
    for (int k = 0; k < 4; k++) {
      int cch = 4 * lane + k;           // channel = f*T + t
      int f = cch / Tt, tt = cch % Tt;
      float val = (k == 0) ? a0 : (k == 1) ? a1 : (k == 2) ? a2 : a3;
      Px16[(size_t)tt * Nn * Ff + (size_t)i * Ff + f] = __float2half(val);
    }
  }
}

// accumulate 8 fp16 channels (one uint4 gather) weighted by wt into a[8]
static __device__ __forceinline__ void acc8_(const uint4& gv, float wt, float* a) {
  float2 f0 = __half22float2(*reinterpret_cast<const __half2*>(&gv.x));
  float2 f1 = __half22float2(*reinterpret_cast<const __half2*>(&gv.y));
  float2 f2 = __half22float2(*reinterpret_cast<const __half2*>(&gv.z));
  float2 f3 = __half22float2(*reinterpret_cast<const __half2*>(&gv.w));
  a[0] = fmaf(wt, f0.x, a[0]); a[1] = fmaf(wt, f0.y, a[1]);
  a[2] = fmaf(wt, f1.x, a[2]); a[3] = fmaf(wt, f1.y, a[3]);
  a[4] = fmaf(wt, f2.x, a[4]); a[5] = fmaf(wt, f2.y, a[5]);
  a[6] = fmaf(wt, f3.x, a[6]); a[7] = fmaf(wt, f3.y, a[7]);
}

// ---------------- XCD-sharded half-channel aggregation ----------------
// vhs/outs are split-major [2][Nn][32] (each half = 3.2 MB, fits one XCD L2).
// half = blockIdx&1; XCD = blockIdx%8 round-robin => even XCDs gather only half 0,
// odd XCDs only half 1 -> gather set L2-resident. Wave per node: 4 lanes x 16B/edge,
// 16 edge slots, unroll 2 (32 edges/iter).
__global__ __launch_bounds__(256) void k_agg2h(
    const __half* __restrict__ vhs, __half* __restrict__ outs,
    const int* __restrict__ rp, const unsigned* __restrict__ edge4,
    const float* __restrict__ dis) {
  const int b = blockIdx.x;
  const int wv = threadIdx.x >> 6, lane = threadIdx.x & 63;
  const int hf = b & 1;
  const int i = (b >> 1) * 4 + wv;   // Nn = 12500*4 exactly
  if (i >= Nn) return;
  const __half* vp = vhs + (size_t)hf * Nn * 32;
  const int g = lane >> 2;  // edge slot 0..15
  const int c = lane & 3;   // channel octet: halves [8c, 8c+8)
  float d = dis[i], sn = d * d;
  float a[8];
  {
    uint4 gv = *(const uint4*)(vp + (size_t)i * 32 + 8 * c);  // self
    float ws = (g == 0) ? sn : 0.f;
    float2 f0 = __half22float2(*reinterpret_cast<const __half2*>(&gv.x));
    float2 f1 = __half22float2(*reinterpret_cast<const __half2*>(&gv.y));
    float2 f2 = __half22float2(*reinterpret_cast<const __half2*>(&gv.z));
    float2 f3 = __half22float2(*reinterpret_cast<const __half2*>(&gv.w));
    a[0] = ws * f0.x; a[1] = ws * f0.y; a[2] = ws * f1.x; a[3] = ws * f1.y;
    a[4] = ws * f2.x; a[5] = ws * f2.y; a[6] = ws * f3.x; a[7] = ws * f3.y;
  }
  int jb = rp[i], je = rp[i + 1];
  for (int j0 = jb; j0 < je; j0 += 32) {
    int j1 = j0 + g, j2 = j0 + 16 + g;
    unsigned e1 = edge4[min(j1, Ee - 1)];
    unsigned e2 = edge4[min(j2, Ee - 1)];
    float w1 = (j1 < je) ? __half2float(__ushort_as_half((unsigned short)(e1 >> 16))) : 0.f;
    float w2 = (j2 < je) ? __half2float(__ushort_as_half((unsigned short)(e2 >> 16))) : 0.f;
    uint4 g1 = *(const uint4*)(vp + (size_t)(e1 & 0xFFFFu) * 32 + 8 * c);
    uint4 g2 = *(const uint4*)(vp + (size_t)(e2 & 0xFFFFu) * 32 + 8 * c);
    acc8_(g1, w1, a);
    acc8_(g2, w2, a);
  }
#pragma unroll
  for (int k2 = 0; k2 < 8; k2++) {
    a[k2] += __shfl_xor(a[k2], 4, 64);
    a[k2] += __shfl_xor(a[k2], 8, 64);
    a[k2] += __shfl_xor(a[k2], 16, 64);
    a[k2] += __shfl_xor(a[k2], 32, 64);
  }
  if (g == 0) {
    __half2 h0 = __floats2half2_rn(a[0], a[1]);
    __half2 h1 = __floats2half2_rn(a[2], a[3]);
    __half2 h2 = __floats2half2_rn(a[4], a[5]);
    __half2 h3 = __floats2half2_rn(a[6], a[7]);
    uint4 st;
    st.x = *reinterpret_cast<unsigned int*>(&h0);
    st.y = *reinterpret_cast<unsigned int*>(&h1);
    st.z = *reinterpret_cast<unsigned int*>(&h2);
    st.w = *reinterpret_cast<unsigned int*>(&h3);
    *(uint4*)(outs + (size_t)hf * Nn * 32 + (size_t)i * 32 + 8 * c) = st;
  }
}

// ---- staging: Px rows [0,16) | Pagg half0 [16,48) | half1 [48,80) | zeros [80,104) ----
static __device__ __forceinline__ void stage_px_pagg_zero(
    __half* sX16, const __half* __restrict__ Px16t, const __half* __restrict__ Pagg,
    int i0, int tid) {
  if (tid < 32) {
    int n = tid >> 1, r = tid & 1;
    *(uint4*)(sX16 + n * 104 + r * 8) =
        *(const uint4*)(Px16t + (size_t)(i0 + n) * Ff + r * 8);
  } else if (tid < 160) {
    int u = tid - 32, n = u >> 3, part = u & 7;  // part 0-3: half0, 4-7: half1
    const __half* src = Pagg + (part >= 4 ? (size_t)Nn * 32 : 0) +
                        (size_t)(i0 + n) * 32 + (part & 3) * 8;
    *(uint4*)(sX16 + n * 104 + 16 + part * 8) = *(const uint4*)src;
  } else if (tid < 208) {
    int p = tid - 160, n = p / 3, part = p % 3;
    *(uint4*)(sX16 + n * 104 + 80 + part * 8) = make_uint4(0u, 0u, 0u, 0u);
  }
}

// ---------------- GEMM z/r via MFMA (agg result from Pagg) ----------------
__global__ __launch_bounds__(256) void k_gemm_zr(
    const __half* __restrict__ Px16, const __half* __restrict__ Pagg,
    const __half* __restrict__ h16s, const __half* __restrict__ frag,
    const float* __restrict__ bz, const float* __restrict__ br,
    __half* __restrict__ zb16, __half* __restrict__ rh16s, int tstep) {
  __shared__ __align__(16) __half sX16[16 * 104];
  const int tid = threadIdx.x;
  const int i0 = blockIdx.x * 16;  // Nn = 3125*16 exactly
  const int wv = tid >> 6, lane = tid & 63;
  f16x8 bzf[3], brf[3];
#pragma unroll
  for (int ks = 0; ks < 3; ks++) {
    bzf[ks] = *(const f16x8*)(frag + ((size_t)(wv * 3 + ks) * 64 + lane) * 8);
    brf[ks] = *(const f16x8*)(frag + ((size_t)((4 + wv) * 3 + ks) * 64 + lane) * 8);
  }
  stage_px_pagg_zero(sX16, Px16 + (size_t)tstep * Nn * Ff, Pagg, i0, tid);
  __syncthreads();
  const int m = lane & 15, q = lane >> 4;
  f32x4 accz = {0.f, 0.f, 0.f, 0.f}, accr = {0.f, 0.f, 0.f, 0.f};
#pragma unroll
  for (int ks = 0; ks < 3; ks++) {
    f16x8 a = *(const f16x8*)(sX16 + m * 104 + ks * 32 + q * 8);
    accz = __builtin_amdgcn_mfma_f32_16x16x32_f16(a, bzf[ks], accz, 0, 0, 0);
    accr = __builtin_amdgcn_mfma_f32_16x16x32_f16(a, brf[ks], accr, 0, 0, 0);
  }
  const int o = wv * 16 + m;
  float bzo = bz[o], bro = br[o];
  const int nb = i0 + q * 4;
  const size_t po = (size_t)(o >> 5) * Nn * 32;
  const int oc = o & 31;
#pragma unroll
  for (int r = 0; r < 4; r++) {
    int node = nb + r;
    float zv = sigmoidf_(accz[r] + bzo);
    float rv = sigmoidf_(accr[r] + bro);
    float hv = __half2float(h16s[po + (size_t)node * 32 + oc]);
    zb16[(size_t)node * Hh + o] = __float2half(zv);
    rh16s[po + (size_t)node * 32 + oc] = __float2half(rv * hv);
  }
}

// ---------------- GEMM h via MFMA + GRU update ----------------
__global__ __launch_bounds__(256) void k_gemm_h(
    const __half* __restrict__ Px16, const __half* __restrict__ Pagg,
    const __half* __restrict__ zb16, float* __restrict__ h, __half* __restrict__ h16s,
    __half* __restrict__ hs16, const __half* __restrict__ frag,
    const float* __restrict__ bh, int tstep) {
  __shared__ __align__(16) __half sX16[16 * 104];
  const int tid = threadIdx.x;
  const int i0 = blockIdx.x * 16;
  const int wv = tid >> 6, lane = tid & 63;
  f16x8 bf[3];
#pragma unroll
  for (int ks = 0; ks < 3; ks++)
    bf[ks] = *(const f16x8*)(frag + ((size_t)((8 + wv) * 3 + ks) * 64 + lane) * 8);
  stage_px_pagg_zero(sX16, Px16 + (size_t)tstep * Nn * Ff, Pagg, i0, tid);
  __syncthreads();
  const int m = lane & 15, q = lane >> 4;
  f32x4 acc = {0.f, 0.f, 0.f, 0.f};
#pragma unroll
  for (int ks = 0; ks < 3; ks++) {
    f16x8 a = *(const f16x8*)(sX16 + m * 104 + ks * 32 + q * 8);
    acc = __builtin_amdgcn_mfma_f32_16x16x32_f16(a, bf[ks], acc, 0, 0, 0);
  }
  const int o = wv * 16 + m;
  float bho = bh[o];
  const int nb = i0 + q * 4;
  __half* hst = hs16 + (size_t)tstep * Nn * Hh;
  const size_t po = (size_t)(o >> 5) * Nn * 32;
  const int oc = o & 31;
#pragma unroll
  for (int r = 0; r < 4; r++) {
    int node = nb + r;
    float hc = tanhf(acc[r] + bho);
    float zv = __half2float(zb16[(size_t)node * Hh + o]);
    float hv = h[(size_t)node * Hh + o];
    float hn = zv * hv + (1.0f - zv) * hc;
    h[(size_t)node * Hh + o] = hn;
    __half hh = __float2half(hn);
    h16s[po + (size_t)node * 32 + oc] = hh;
    hst[(size_t)node * Hh + o] = hh;
  }
}

// ---------------- attention + output via MFMA: wave per node ----------------
__global__ __launch_bounds__(256) void k_att(
    const __half* __restrict__ hs16, const __half* __restrict__ fragA,
    const float* __restrict__ ba, const float* __restrict__ cv,
    const float* __restrict__ Wfc, const float* __restrict__ bfc,
    float* __restrict__ out) {
  const int tid = threadIdx.x;
  const int wv = tid >> 6, lane = tid & 63;
  const int i = blockIdx.x * 4 + wv;
  if (i >= Nn) return;
  const int m = lane & 15, q = lane >> 4;

  f16x8 bf[4][2];
#pragma unroll
  for (int s = 0; s < 8; s++)
    bf[s >> 1][s & 1] = *(const f16x8*)(fragA + (size_t)(s * 64 + lane) * 8);

  const int tm = (m < Tt) ? m : (Tt - 1);
  const __half* hbase = hs16 + (size_t)tm * Nn * Hh + (size_t)i * Hh;
  f16x8 a0 = *(const f16x8*)(hbase + q * 8);
  f16x8 a1 = *(const f16x8*)(hbase + 32 + q * 8);

  f32x4 acc[4];
#pragma unroll
  for (int tile = 0; tile < 4; tile++) acc[tile] = f32x4{0.f, 0.f, 0.f, 0.f};
#pragma unroll
  for (int tile = 0; tile < 4; tile++) {
    acc[tile] = __builtin_amdgcn_mfma_f32_16x16x32_f16(a0, bf[tile][0], acc[tile], 0, 0, 0);
    acc[tile] = __builtin_amdgcn_mfma_f32_16x16x32_f16(a1, bf[tile][1], acc[tile], 0, 0, 0);
  }

  float ba_l[4], cv_l[4];
#pragma unroll
  for (int tile = 0; tile < 4; tile++) {
    ba_l[tile] = ba[tile * 16 + m];
    cv_l[tile] = cv[tile * 16 + m];
  }
  float ar[4];
#pragma unroll
  for (int r = 0; r < 4; r++) {
    float s = 0.f;
#pragma unroll
    for (int tile = 0; tile < 4; tile++)
      s += tanhf(acc[tile][r] + ba_l[tile]) * cv_l[tile];
    s += __shfl_xor(s, 1, 64);
    s += __shfl_xor(s, 2, 64);
    s += __shfl_xor(s, 4, 64);
    s += __shfl_xor(s, 8, 64);
    ar[r] = s;
  }
  float al[Tt];
#pragma unroll
  for (int t = 0; t < Tt; t++) al[t] = __shfl(ar[t & 3], (t >> 2) * 16, 64);
  float mx = al[0];
#pragma unroll
  for (int t = 1; t < Tt; t++) mx = fmaxf(mx, al[t]);
  float ssum = 0.f;
#pragma unroll
  for (int t = 0; t < Tt; t++) { al[t] = expf(al[t] - mx); ssum += al[t]; }
  float inv = 1.0f / ssum;
  float cx = 0.f;
#pragma unroll
  for (int t = 0; t < Tt; t++)
    cx = fmaf(al[t], __half2float(hs16[(size_t)t * Nn * Hh + (size_t)i * Hh + lane]), cx);
  float p = cx * inv * Wfc[lane];
#pragma unroll
  for (int off = 32; off >= 1; off >>= 1) p += __shfl_xor(p, off, 64);
  if (lane == 0) out[i] = p + bfc[0];
}

extern "C" void kernel_launch(void* const* d_in, const int* in_sizes, int n_in,
                              void* d_out, int out_size, void* d_ws, size_t ws_size,
                              hipStream_t stream) {
  const float* x   = (const float*)d_in[0];
  const int* ei    = (const int*)d_in[1];
  const float* ew  = (const float*)d_in[2];
  const float* Wz  = (const float*)d_in[3];
  const float* bz  = (const float*)d_in[4];
  const float* Wr  = (const float*)d_in[5];
  const float* br  = (const float*)d_in[6];
  const float* Wh  = (const float*)d_in[7];
  const float* bh  = (const float*)d_in[8];
  const float* Wa  = (const float*)d_in[9];
  const float* ba  = (const float*)d_in[10];
  const float* cv  = (const float*)d_in[11];
  const float* Wfc = (const float*)d_in[12];
  const float* bfc = (const float*)d_in[13];
  float* out = (float*)d_out;

  char* w = (char*)d_ws;
  auto alloc = [&](size_t bytes) {
    char* p = w;
    w += (bytes + 255) & ~(size_t)255;
    return p;
  };
  unsigned long long* dc = (unsigned long long*)alloc((size_t)Nn * 8);
  float* dis = (float*)alloc((size_t)Nn * 4);
  int* cnt   = (int*)alloc((size_t)Nn * 4);
  int* rp    = (int*)alloc((size_t)(Nn + 1) * 4);
  int* cur   = (int*)alloc((size_t)Nn * 4);
  int* bsum  = (int*)alloc((size_t)SCAN_NB * 4);
  int* boff  = (int*)alloc((size_t)SCAN_NB * 4);
  int2* edge2 = (int2*)alloc((size_t)Ee * 8);
  unsigned* edge4 = (unsigned*)alloc((size_t)Ee * 4);
  __half* x16  = (__half*)alloc((size_t)Nn * Ff * Tt * 2);
  __half* Px16 = (__half*)alloc((size_t)Tt * Nn * Ff * 2);
  float* h     = (float*)alloc((size_t)Nn * Hh * 4);
  __half* h16s  = (__half*)alloc((size_t)2 * Nn * 32 * 2);  // split [2][Nn][32]
  __half* rh16s = (__half*)alloc((size_t)2 * Nn * 32 * 2);  // split [2][Nn][32]
  __half* zb16 = (__half*)alloc((size_t)Nn * Hh * 2);
  __half* Pagg = (__half*)alloc((size_t)2 * Nn * 32 * 2);   // agg scratch, split
  __half* hs16 = (__half*)alloc((size_t)Tt * Nn * Hh * 2);  // 76.8 MB history
  __half* wfrag = (__half*)alloc((size_t)12 * 3 * 64 * 8 * 2);
  __half* wfragA = (__half*)alloc((size_t)8 * 64 * 8 * 2);

  hipMemsetAsync(dc, 0, (size_t)Nn * 8, stream);
  hipMemsetAsync(h, 0, (size_t)Nn * Hh * 4, stream);
  hipMemsetAsync(h16s, 0, (size_t)2 * Nn * 32 * 2, stream);  // fp16 zero == 0x0000

  k_deg<<<(Ee + 255) / 256, 256, 0, stream>>>(ei, ew, dc);
  k_dis<<<(Nn + 255) / 256, 256, 0, stream>>>(dc, dis, cnt);
  k_scan1<<<SCAN_NB, 256, 0, stream>>>(cnt, bsum);
  k_scan2<<<1, 128, 0, stream>>>(bsum, boff);
  k_scan3<<<SCAN_NB, 256, 0, stream>>>(cnt, boff, rp, cur);
  k_scatter<<<(Ee + 255) / 256, 256, 0, stream>>>(ei, ew, dis, cur, edge2);
  k_pack<<<(Ee + 255) / 256, 256, 0, stream>>>(edge2, edge4);
  {
    const size_t total = (size_t)Nn * Ff * Tt;
    k_cvt_x<<<(int)((total + 255) / 256), 256, 0, stream>>>(x, x16);
  }
  k_wfrag<<<9, 256, 0, stream>>>(Wz, Wr, Wh, wfrag);
  k_wfrag_a<<<2, 256, 0, stream>>>(Wa, wfragA);
  k_agg_px<<<(Nn + 3) / 4, 256, 0, stream>>>(x, x16, Px16, rp, edge2, dis);

  const int gGemm = Nn / 16;       // 3125 blocks
  const int gAgg = (Nn / 4) * 2;   // 25000 blocks: half = blockIdx&1 (XCD parity)
  const int gNode = (Nn + 3) / 4;
  for (int t = 0; t < Tt; t++) {
    k_agg2h<<<gAgg, 256, 0, stream>>>(h16s, Pagg, rp, edge4, dis);
    k_gemm_zr<<<gGemm, 256, 0, stream>>>(Px16, Pagg, h16s, wfrag, bz, br,
                                         zb16, rh16s, t);
    k_agg2h<<<gAgg, 256, 0, stream>>>(rh16s, Pagg, rp, edge4, dis);
    k_gemm_h<<<gGemm, 256, 0, stream>>>(Px16, Pagg, zb16, h, h16s, hs16, wfrag, bh, t);
  }
  k_att<<<gNode, 256, 0, stream>>>(hs16, wfragA, ba, cv, Wfc, bfc, out);
}

// Round 8
// 1461.627 us; speedup vs baseline: 1.1046x; 1.1046x over previous
//
#include <hip/hip_runtime.h>
#include <hip/hip_fp16.h>
#include <math.h>

#define Nn 50000
#define Ff 16
#define Tt 12
#define Hh 64
#define Ee 1600000
#define Cc 80  // F + H

#define SCAN_NB 98  // ceil(50000 / 512)

typedef _Float16 f16x8 __attribute__((ext_vector_type(8)));
typedef float f32x4 __attribute__((ext_vector_type(4)));

static __device__ __forceinline__ float sigmoidf_(float x) { return 1.0f / (1.0f + expf(-x)); }

// ---------------- CSR build ----------------
__global__ void k_deg(const int* __restrict__ ei, const float* __restrict__ ew,
                      unsigned long long* __restrict__ dc) {
  int e = blockIdx.x * blockDim.x + threadIdx.x;
  if (e >= Ee) return;
  int d = ei[Ee + e];
  unsigned long long pk = (1ULL << 42) + (unsigned long long)(ew[e] * 2097152.0f + 0.5f);
  atomicAdd(&dc[d], pk);
}

__global__ void k_dis(const unsigned long long* __restrict__ dc,
                      float* __restrict__ dis, int* __restrict__ cnt) {
  int i = blockIdx.x * blockDim.x + threadIdx.x;
  if (i >= Nn) return;
  unsigned long long v = dc[i];
  cnt[i] = (int)(v >> 42);
  float deg = (float)(v & ((1ULL << 42) - 1)) * (1.0f / 2097152.0f);
  dis[i] = 1.0f / sqrtf(deg + 1.0f);
}

// ---- multi-block exclusive scan of cnt[Nn] -> rp/cur ----
__global__ __launch_bounds__(256) void k_scan1(const int* __restrict__ cnt,
                                               int* __restrict__ bsum) {
  __shared__ int ss[256];
  int b = blockIdx.x, t = threadIdx.x;
  int base = b * 512 + t * 2;
  int s = 0;
  if (base < Nn) s += cnt[base];
  if (base + 1 < Nn) s += cnt[base + 1];
  ss[t] = s;
  __syncthreads();
  for (int off = 128; off > 0; off >>= 1) {
    if (t < off) ss[t] += ss[t + off];
    __syncthreads();
  }
  if (t == 0) bsum[b] = ss[0];
}

__global__ __launch_bounds__(128) void k_scan2(const int* __restrict__ bsum,
                                               int* __restrict__ boff) {
  __shared__ int ss[128];
  int t = threadIdx.x;
  int v = (t < SCAN_NB) ? bsum[t] : 0;
  ss[t] = v;
  __syncthreads();
  for (int off = 1; off < 128; off <<= 1) {
    int u = (t >= off) ? ss[t - off] : 0;
    __syncthreads();
    ss[t] += u;
    __syncthreads();
  }
  if (t < SCAN_NB) boff[t] = ss[t] - v;  // exclusive
}

__global__ __launch_bounds__(256) void k_scan3(const int* __restrict__ cnt,
                                               const int* __restrict__ boff,
                                               int* __restrict__ rp, int* __restrict__ cur) {
  __shared__ int ss[256];
  int b = blockIdx.x, t = threadIdx.x;
  int base = b * 512 + t * 2;
  int c0 = (base < Nn) ? cnt[base] : 0;
  int c1 = (base + 1 < Nn) ? cnt[base + 1] : 0;
  int s = c0 + c1;
  ss[t] = s;
  __syncthreads();
  for (int off = 1; off < 256; off <<= 1) {
    int u = (t >= off) ? ss[t - off] : 0;
    __syncthreads();
    ss[t] += u;
    __syncthreads();
  }
  int run = boff[b] + ss[t] - s;
  if (base < Nn) { rp[base] = run; cur[base] = run; }
  if (base + 1 < Nn) { rp[base + 1] = run + c0; cur[base + 1] = run + c0; }
  if (b == 0 && t == 0) rp[Nn] = Ee;
}

// edge2[pos] = {src, normalized fp32 weight}: ONE scattered 8-B store per edge
__global__ void k_scatter(const int* __restrict__ ei, const float* __restrict__ ew,
                          const float* __restrict__ dis, int* __restrict__ cur,
                          int2* __restrict__ edge2) {
  int e = blockIdx.x * blockDim.x + threadIdx.x;
  if (e >= Ee) return;
  int s = ei[e];
  int d = ei[Ee + e];
  float w = ew[e] * dis[s] * dis[d];
  int pos = atomicAdd(&cur[d], 1);
  edge2[pos] = make_int2(s, __float_as_int(w));
}

// edge4[e] = u16 src | fp16 w << 16 (sequential read/write; no second scatter stream)
__global__ void k_pack(const int2* __restrict__ edge2, unsigned* __restrict__ edge4) {
  int e = blockIdx.x * blockDim.x + threadIdx.x;
  if (e >= Ee) return;
  int2 v = edge2[e];
  __half wh = __float2half(__int_as_float(v.y));
  edge4[e] = (unsigned)(v.x & 0xFFFF) | ((unsigned)__half_as_ushort(wh) << 16);
}

// ---------------- x fp32 -> fp16 (once) ----------------
__global__ void k_cvt_x(const float* __restrict__ x, __half* __restrict__ x16) {
  size_t idx = (size_t)blockIdx.x * blockDim.x + threadIdx.x;
  const size_t total = (size_t)Nn * Ff * Tt;
  if (idx < total) x16[idx] = __float2half(x[idx]);
}

// ---------------- weight fragments for MFMA (once) ----------------
__global__ void k_wfrag(const float* __restrict__ Wz, const float* __restrict__ Wr,
                        const float* __restrict__ Wh, __half* __restrict__ frag) {
  int t = blockIdx.x * 256 + threadIdx.x;
  if (t >= 12 * 3 * 64) return;
  int s = t / 192, rem = t % 192, ks = rem / 64, lane = rem % 64;
  int q = lane >> 4, nl = lane & 15;
  const float* W = (s < 4) ? Wz : (s < 8) ? Wr : Wh;
  int n0 = (s & 3) * 16;
  __half tmp[8];
#pragma unroll
  for (int j = 0; j < 8; j++) {
    int k = ks * 32 + q * 8 + j;
    float v = (k < Cc) ? W[k * Hh + n0 + nl] : 0.f;
    tmp[j] = __float2half(v);
  }
  *(uint4*)(frag + ((size_t)(s * 3 + ks) * 64 + lane) * 8) = *(uint4*)tmp;
}

__global__ void k_wfrag_a(const float* __restrict__ Wa, __half* __restrict__ fragA) {
  int t = blockIdx.x * 256 + threadIdx.x;
  if (t >= 8 * 64) return;
  int s = t >> 6, lane = t & 63;
  int tile = s >> 1, ks = s & 1;
  int q = lane >> 4, m = lane & 15;
  __half tmp[8];
#pragma unroll
  for (int j = 0; j < 8; j++) {
    int k = ks * 32 + q * 8 + j;
    tmp[j] = __float2half(Wa[k * Hh + tile * 16 + m]);
  }
  *(uint4*)(fragA + ((size_t)t) * 8) = *(uint4*)tmp;
}

// ---------------- Px16[t][i][f] = (A_hat @ x): wave per node, 48 lanes x 8B per edge ----------------
__global__ __launch_bounds__(256) void k_agg_px(
    const float* __restrict__ x, const __half* __restrict__ x16, __half* __restrict__ Px16,
    const int* __restrict__ rp, const int2* __restrict__ edge2,
    const float* __restrict__ dis) {
  int i = blockIdx.x * 4 + (threadIdx.x >> 6);
  if (i >= Nn) return;
  int lane = threadIdx.x & 63;
  const int R = Ff * Tt;  // 192
  const bool act = lane < 48;
  float d = dis[i], sn = d * d;
  float a0 = 0.f, a1 = 0.f, a2 = 0.f, a3 = 0.f;
  if (act) {
    float4 sv = *(const float4*)(x + (size_t)i * R + 4 * lane);  // self, fp32 exact
    a0 = sn * sv.x; a1 = sn * sv.y; a2 = sn * sv.z; a3 = sn * sv.w;
  }
  int jb = rp[i], je = rp[i + 1];
  for (int j = jb; j < je; j += 2) {
    int jc1 = min(j + 1, Ee - 1);
    int2 e0 = edge2[j];
    int2 e1 = edge2[jc1];
    float w0 = __int_as_float(e0.y);
    float w1 = (j + 1 < je) ? __int_as_float(e1.y) : 0.f;
    if (act) {
      uint2 g0 = *(const uint2*)(x16 + (size_t)e0.x * R + 4 * lane);
      uint2 g1 = *(const uint2*)(x16 + (size_t)e1.x * R + 4 * lane);
      float2 p01 = __half22float2(*reinterpret_cast<const __half2*>(&g0.x));
      float2 p23 = __half22float2(*reinterpret_cast<const __half2*>(&g0.y));
      float2 q01 = __half22float2(*reinterpret_cast<const __half2*>(&g1.x));
      float2 q23 = __half22float2(*reinterpret_cast<const __half2*>(&g1.y));
      a0 = fmaf(w0, p01.x, a0); a1 = fmaf(w0, p01.y, a1);
      a2 = fmaf(w0, p23.x, a2); a3 = fmaf(w0, p23.y, a3);
      a0 = fmaf(w1, q01.x, a0); a1 = fmaf(w1, q01.y, a1);
      a2 = fmaf(w1, q23.x, a2); a3 = fmaf(w1, q23.y, a3);
    }
  }
  if (act) {
#pragma unroll
    for (int k = 0; k < 4; k++) {
      int cch = 4 * lane + k;           // channel = f*T + t
      int f = cch / Tt, tt = cch % Tt;
      float val = (k == 0) ? a0 : (k == 1) ? a1 : (k == 2) ? a2 : a3;
      Px16[(size_t)tt * Nn * Ff + (size_t)i * Ff + f] = __float2half(val);
    }
  }
}

// ---- shared staging: Px rows (halves [0,16)) + zero tail (halves [80,104)) ----
static __device__ __forceinline__ void stage_px_zero(
    __half* sX16, const __half* __restrict__ Px16t, int i0, int tid) {
  if (tid < 32) {
    int n = tid >> 1, r = tid & 1;
    *(uint4*)(sX16 + n * 104 + r * 8) =
        *(const uint4*)(Px16t + (size_t)(i0 + n) * Ff + r * 8);
  } else if (tid < 80) {
    int p = tid - 32, n = p / 3, part = p % 3;
    *(uint4*)(sX16 + n * 104 + 80 + part * 8) = make_uint4(0u, 0u, 0u, 0u);
  }
}

// accumulate 8 fp16 channels (one uint4 gather) weighted by wt into a[8]
static __device__ __forceinline__ void acc8_(const uint4& gv, float wt, float* a) {
  float2 f0 = __half22float2(*reinterpret_cast<const __half2*>(&gv.x));
  float2 f1 = __half22float2(*reinterpret_cast<const __half2*>(&gv.y));
  float2 f2 = __half22float2(*reinterpret_cast<const __half2*>(&gv.z));
  float2 f3 = __half22float2(*reinterpret_cast<const __half2*>(&gv.w));
  a[0] = fmaf(wt, f0.x, a[0]); a[1] = fmaf(wt, f0.y, a[1]);
  a[2] = fmaf(wt, f1.x, a[2]); a[3] = fmaf(wt, f1.y, a[3]);
  a[4] = fmaf(wt, f2.x, a[4]); a[5] = fmaf(wt, f2.y, a[5]);
  a[6] = fmaf(wt, f3.x, a[6]); a[7] = fmaf(wt, f3.y, a[7]);
}

// ---- aggregation core: 8 lanes/edge x 16B, 8 edge slots, 4-deep (32 edges/iter) ----
// Out-of-range slots are PREDICATED (exec-masked): no junk gather traffic.
// (Poisson(32) degrees made clamped junk loads ~45% of gather bytes before.)
static __device__ __forceinline__ void agg_node_to_lds(
    __half* sX16, int n, int i, int lane,
    const __half* __restrict__ v, const int* __restrict__ rp,
    const unsigned* __restrict__ edge4, const float* __restrict__ dis) {
  int g = lane >> 3;   // edge slot 0..7
  int c = lane & 7;    // channel octet: halves [8c, 8c+8)
  float d = dis[i], sn = d * d;
  float a[8];
  {
    uint4 gv = *(const uint4*)(v + (size_t)i * Hh + 8 * c);  // self
    float ws = (g == 0) ? sn : 0.f;
    float2 f0 = __half22float2(*reinterpret_cast<const __half2*>(&gv.x));
    float2 f1 = __half22float2(*reinterpret_cast<const __half2*>(&gv.y));
    float2 f2 = __half22float2(*reinterpret_cast<const __half2*>(&gv.z));
    float2 f3 = __half22float2(*reinterpret_cast<const __half2*>(&gv.w));
    a[0] = ws * f0.x; a[1] = ws * f0.y; a[2] = ws * f1.x; a[3] = ws * f1.y;
    a[4] = ws * f2.x; a[5] = ws * f2.y; a[6] = ws * f3.x; a[7] = ws * f3.y;
  }
  int jb = rp[i], je = rp[i + 1];
  for (int j0 = jb; j0 < je; j0 += 32) {
    int j1 = j0 + g, j2 = j0 + 8 + g, j3 = j0 + 16 + g, j4 = j0 + 24 + g;
    if (j1 < je) {
      unsigned e1 = edge4[j1];
      float w1 = __half2float(__ushort_as_half((unsigned short)(e1 >> 16)));
      uint4 g1 = *(const uint4*)(v + (size_t)(e1 & 0xFFFFu) * Hh + 8 * c);
      acc8_(g1, w1, a);
    }
    if (j2 < je) {
      unsigned e2 = edge4[j2];
      float w2 = __half2float(__ushort_as_half((unsigned short)(e2 >> 16)));
      uint4 g2 = *(const uint4*)(v + (size_t)(e2 & 0xFFFFu) * Hh + 8 * c);
      acc8_(g2, w2, a);
    }
    if (j3 < je) {
      unsigned e3 = edge4[j3];
      float w3 = __half2float(__ushort_as_half((unsigned short)(e3 >> 16)));
      uint4 g3 = *(const uint4*)(v + (size_t)(e3 & 0xFFFFu) * Hh + 8 * c);
      acc8_(g3, w3, a);
    }
    if (j4 < je) {
      unsigned e4 = edge4[j4];
      float w4 = __half2float(__ushort_as_half((unsigned short)(e4 >> 16)));
      uint4 g4 = *(const uint4*)(v + (size_t)(e4 & 0xFFFFu) * Hh + 8 * c);
      acc8_(g4, w4, a);
    }
  }
#pragma unroll
  for (int k2 = 0; k2 < 8; k2++) {
    a[k2] += __shfl_xor(a[k2], 8, 64);
    a[k2] += __shfl_xor(a[k2], 16, 64);
    a[k2] += __shfl_xor(a[k2], 32, 64);
  }
  if (g == 0) {
    __half2 h0 = __floats2half2_rn(a[0], a[1]);
    __half2 h1 = __floats2half2_rn(a[2], a[3]);
    __half2 h2 = __floats2half2_rn(a[4], a[5]);
    __half2 h3 = __floats2half2_rn(a[6], a[7]);
    uint4 st;
    st.x = *reinterpret_cast<unsigned int*>(&h0);
    st.y = *reinterpret_cast<unsigned int*>(&h1);
    st.z = *reinterpret_cast<unsigned int*>(&h2);
    st.w = *reinterpret_cast<unsigned int*>(&h3);
    *(uint4*)(sX16 + n * 104 + 16 + 8 * c) = st;  // 8 lanes x 16B contiguous
  }
}

// ---------------- FUSED agg(h16) + GEMM z/r ----------------
__global__ __launch_bounds__(256) void k_zr_f(
    const __half* __restrict__ Px16, const __half* __restrict__ h16,
    const __half* __restrict__ frag,
    const float* __restrict__ bz, const float* __restrict__ br,
    const int* __restrict__ rp, const unsigned* __restrict__ edge4,
    const float* __restrict__ dis,
    __half* __restrict__ zb16, __half* __restrict__ rh16, int tstep) {
  __shared__ __align__(16) __half sX16[16 * 104];
  const int tid = threadIdx.x;
  const int i0 = blockIdx.x * 16;  // Nn = 3125*16 exactly
  const int wv = tid >> 6, lane = tid & 63;
  stage_px_zero(sX16, Px16 + (size_t)tstep * Nn * Ff, i0, tid);
#pragma unroll
  for (int k = 0; k < 4; k++) {
    int n = wv * 4 + k;
    agg_node_to_lds(sX16, n, i0 + n, lane, h16, rp, edge4, dis);
  }
  __syncthreads();
  // b-fragments loaded AFTER the agg phase: fewer live VGPRs during gathers
  f16x8 bzf[3], brf[3];
#pragma unroll
  for (int ks = 0; ks < 3; ks++) {
    bzf[ks] = *(const f16x8*)(frag + ((size_t)(wv * 3 + ks) * 64 + lane) * 8);
    brf[ks] = *(const f16x8*)(frag + ((size_t)((4 + wv) * 3 + ks) * 64 + lane) * 8);
  }
  const int m = lane & 15, q = lane >> 4;
  f32x4 accz = {0.f, 0.f, 0.f, 0.f}, accr = {0.f, 0.f, 0.f, 0.f};
#pragma unroll
  for (int ks = 0; ks < 3; ks++) {
    f16x8 a = *(const f16x8*)(sX16 + m * 104 + ks * 32 + q * 8);
    accz = __builtin_amdgcn_mfma_f32_16x16x32_f16(a, bzf[ks], accz, 0, 0, 0);
    accr = __builtin_amdgcn_mfma_f32_16x16x32_f16(a, brf[ks], accr, 0, 0, 0);
  }
  const int o = wv * 16 + m;
  float bzo = bz[o], bro = br[o];
  const int nb = i0 + q * 4;
#pragma unroll
  for (int r = 0; r < 4; r++) {
    int node = nb + r;
    float zv = sigmoidf_(accz[r] + bzo);
    float rv = sigmoidf_(accr[r] + bro);
    float hv = __half2float(h16[(size_t)node * Hh + o]);
    zb16[(size_t)node * Hh + o] = __float2half(zv);
    rh16[(size_t)node * Hh + o] = __float2half(rv * hv);
  }
}

// ---------------- FUSED agg(rh16) + GEMM h + GRU update ----------------
__global__ __launch_bounds__(256) void k_h_f(
    const __half* __restrict__ Px16, const __half* __restrict__ rh16,
    const __half* __restrict__ zb16, float* __restrict__ h, __half* __restrict__ h16,
    __half* __restrict__ hs16, const __half* __restrict__ frag,
    const float* __restrict__ bh,
    const int* __restrict__ rp, const unsigned* __restrict__ edge4,
    const float* __restrict__ dis, int tstep) {
  __shared__ __align__(16) __half sX16[16 * 104];
  const int tid = threadIdx.x;
  const int i0 = blockIdx.x * 16;
  const int wv = tid >> 6, lane = tid & 63;
  stage_px_zero(sX16, Px16 + (size_t)tstep * Nn * Ff, i0, tid);
#pragma unroll
  for (int k = 0; k < 4; k++) {
    int n = wv * 4 + k;
    agg_node_to_lds(sX16, n, i0 + n, lane, rh16, rp, edge4, dis);
  }
  __syncthreads();
  f16x8 bf[3];
#pragma unroll
  for (int ks = 0; ks < 3; ks++)
    bf[ks] = *(const f16x8*)(frag + ((size_t)((8 + wv) * 3 + ks) * 64 + lane) * 8);
  const int m = lane & 15, q = lane >> 4;
  f32x4 acc = {0.f, 0.f, 0.f, 0.f};
#pragma unroll
  for (int ks = 0; ks < 3; ks++) {
    f16x8 a = *(const f16x8*)(sX16 + m * 104 + ks * 32 + q * 8);
    acc = __builtin_amdgcn_mfma_f32_16x16x32_f16(a, bf[ks], acc, 0, 0, 0);
  }
  const int o = wv * 16 + m;
  float bho = bh[o];
  const int nb = i0 + q * 4;
  __half* hst = hs16 + (size_t)tstep * Nn * Hh;
#pragma unroll
  for (int r = 0; r < 4; r++) {
    int node = nb + r;
    float hc = tanhf(acc[r] + bho);
    float zv = __half2float(zb16[(size_t)node * Hh + o]);
    float hv = h[(size_t)node * Hh + o];
    float hn = zv * hv + (1.0f - zv) * hc;
    h[(size_t)node * Hh + o] = hn;
    __half hh = __float2half(hn);
    h16[(size_t)node * Hh + o] = hh;
    hst[(size_t)node * Hh + o] = hh;
  }
}

// ---------------- attention + output via MFMA: wave per node ----------------
__global__ __launch_bounds__(256) void k_att(
    const __half* __restrict__ hs16, const __half* __restrict__ fragA,
    const float* __restrict__ ba, const float* __restrict__ cv,
    const float* __restrict__ Wfc, const float* __restrict__ bfc,
    float* __restrict__ out) {
  const int tid = threadIdx.x;
  const int wv = tid >> 6, lane = tid & 63;
  const int i = blockIdx.x * 4 + wv;
  if (i >= Nn) return;
  const int m = lane & 15, q = lane >> 4;

  f16x8 bf[4][2];
#pragma unroll
  for (int s = 0; s < 8; s++)
    bf[s >> 1][s & 1] = *(const f16x8*)(fragA + (size_t)(s * 64 + lane) * 8);

  const int tm = (m < Tt) ? m : (Tt - 1);
  const __half* hbase = hs16 + (size_t)tm * Nn * Hh + (size_t)i * Hh;
  f16x8 a0 = *(const f16x8*)(hbase + q * 8);
  f16x8 a1 = *(const f16x8*)(hbase + 32 + q * 8);

  f32x4 acc[4];
#pragma unroll
  for (int tile = 0; tile < 4; tile++) acc[tile] = f32x4{0.f, 0.f, 0.f, 0.f};
#pragma unroll
  for (int tile = 0; tile < 4; tile++) {
    acc[tile] = __builtin_amdgcn_mfma_f32_16x16x32_f16(a0, bf[tile][0], acc[tile], 0, 0, 0);
    acc[tile] = __builtin_amdgcn_mfma_f32_16x16x32_f16(a1, bf[tile][1], acc[tile], 0, 0, 0);
  }

  float ba_l[4], cv_l[4];
#pragma unroll
  for (int tile = 0; tile < 4; tile++) {
    ba_l[tile] = ba[tile * 16 + m];
    cv_l[tile] = cv[tile * 16 + m];
  }
  float ar[4];
#pragma unroll
  for (int r = 0; r < 4; r++) {
    float s = 0.f;
#pragma unroll
    for (int tile = 0; tile < 4; tile++)
      s += tanhf(acc[tile][r] + ba_l[tile]) * cv_l[tile];
    s += __shfl_xor(s, 1, 64);
    s += __shfl_xor(s, 2, 64);
    s += __shfl_xor(s, 4, 64);
    s += __shfl_xor(s, 8, 64);
    ar[r] = s;
  }
  float al[Tt];
#pragma unroll
  for (int t = 0; t < Tt; t++) al[t] = __shfl(ar[t & 3], (t >> 2) * 16, 64);
  float mx = al[0];
#pragma unroll
  for (int t = 1; t < Tt; t++) mx = fmaxf(mx, al[t]);
  float ssum = 0.f;
#pragma unroll
  for (int t = 0; t < Tt; t++) { al[t] = expf(al[t] - mx); ssum += al[t]; }
  float inv = 1.0f / ssum;
  float cx = 0.f;
#pragma unroll
  for (int t = 0; t < Tt; t++)
    cx = fmaf(al[t], __half2float(hs16[(size_t)t * Nn * Hh + (size_t)i * Hh + lane]), cx);
  float p = cx * inv * Wfc[lane];
#pragma unroll
  for (int off = 32; off >= 1; off >>= 1) p += __shfl_xor(p, off, 64);
  if (lane == 0) out[i] = p + bfc[0];
}

extern "C" void kernel_launch(void* const* d_in, const int* in_sizes, int n_in,
                              void* d_out, int out_size, void* d_ws, size_t ws_size,
                              hipStream_t stream) {
  const float* x   = (const float*)d_in[0];
  const int* ei    = (const int*)d_in[1];
  const float* ew  = (const float*)d_in[2];
  const float* Wz  = (const float*)d_in[3];
  const float* bz  = (const float*)d_in[4];
  const float* Wr  = (const float*)d_in[5];
  const float* br  = (const float*)d_in[6];
  const float* Wh  = (const float*)d_in[7];
  const float* bh  = (const float*)d_in[8];
  const float* Wa  = (const float*)d_in[9];
  const float* ba  = (const float*)d_in[10];
  const float* cv  = (const float*)d_in[11];
  const float* Wfc = (const float*)d_in[12];
  const float* bfc = (const float*)d_in[13];
  float* out = (float*)d_out;

  char* w = (char*)d_ws;
  auto alloc = [&](size_t bytes) {
    char* p = w;
    w += (bytes + 255) & ~(size_t)255;
    return p;
  };
  unsigned long long* dc = (unsigned long long*)alloc((size_t)Nn * 8);
  float* dis = (float*)alloc((size_t)Nn * 4);
  int* cnt   = (int*)alloc((size_t)Nn * 4);
  int* rp    = (int*)alloc((size_t)(Nn + 1) * 4);
  int* cur   = (int*)alloc((size_t)Nn * 4);
  int* bsum  = (int*)alloc((size_t)SCAN_NB * 4);
  int* boff  = (int*)alloc((size_t)SCAN_NB * 4);
  int2* edge2 = (int2*)alloc((size_t)Ee * 8);
  unsigned* edge4 = (unsigned*)alloc((size_t)Ee * 4);
  __half* x16  = (__half*)alloc((size_t)Nn * Ff * Tt * 2);
  __half* Px16 = (__half*)alloc((size_t)Tt * Nn * Ff * 2);
  float* h     = (float*)alloc((size_t)Nn * Hh * 4);
  __half* h16  = (__half*)alloc((size_t)Nn * Hh * 2);
  __half* rh16 = (__half*)alloc((size_t)Nn * Hh * 2);
  __half* zb16 = (__half*)alloc((size_t)Nn * Hh * 2);
  __half* hs16 = (__half*)alloc((size_t)Tt * Nn * Hh * 2);  // 76.8 MB history
  __half* wfrag = (__half*)alloc((size_t)12 * 3 * 64 * 8 * 2);
  __half* wfragA = (__half*)alloc((size_t)8 * 64 * 8 * 2);

  hipMemsetAsync(dc, 0, (size_t)Nn * 8, stream);
  hipMemsetAsync(h, 0, (size_t)Nn * Hh * 4, stream);
  hipMemsetAsync(h16, 0, (size_t)Nn * Hh * 2, stream);  // fp16 zero == 0x0000

  k_deg<<<(Ee + 255) / 256, 256, 0, stream>>>(ei, ew, dc);
  k_dis<<<(Nn + 255) / 256, 256, 0, stream>>>(dc, dis, cnt);
  k_scan1<<<SCAN_NB, 256, 0, stream>>>(cnt, bsum);
  k_scan2<<<1, 128, 0, stream>>>(bsum, boff);
  k_scan3<<<SCAN_NB, 256, 0, stream>>>(cnt, boff, rp, cur);
  k_scatter<<<(Ee + 255) / 256, 256, 0, stream>>>(ei, ew, dis, cur, edge2);
  k_pack<<<(Ee + 255) / 256, 256, 0, stream>>>(edge2, edge4);
  {
    const size_t total = (size_t)Nn * Ff * Tt;
    k_cvt_x<<<(int)((total + 255) / 256), 256, 0, stream>>>(x, x16);
  }
  k_wfrag<<<9, 256, 0, stream>>>(Wz, Wr, Wh, wfrag);
  k_wfrag_a<<<2, 256, 0, stream>>>(Wa, wfragA);
  k_agg_px<<<(Nn + 3) / 4, 256, 0, stream>>>(x, x16, Px16, rp, edge2, dis);

  const int gGemm = Nn / 16;  // 3125 blocks, 16 nodes each (exact)
  const int gNode = (Nn + 3) / 4;
  for (int t = 0; t < Tt; t++) {
    k_zr_f<<<gGemm, 256, 0, stream>>>(Px16, h16, wfrag, bz, br, rp, edge4, dis,
                                      zb16, rh16, t);
    k_h_f<<<gGemm, 256, 0, stream>>>(Px16, rh16, zb16, h, h16, hs16, wfrag, bh,
                                     rp, edge4, dis, t);
  }
  k_att<<<gNode, 256, 0, stream>>>(hs16, wfragA, ba, cv, Wfc, bfc, out);
}

// Round 9
// 1326.680 us; speedup vs baseline: 1.2169x; 1.1017x over previous
//
#include <hip/hip_runtime.h>
#include <hip/hip_fp16.h>
#include <math.h>

#define Nn 50000
#define Ff 16
#define Tt 12
#define Hh 64
#define Ee 1600000
#define Cc 80  // F + H

#define SCAN_NB 98  // ceil(50000 / 512)

typedef _Float16 f16x8 __attribute__((ext_vector_type(8)));
typedef float f32x4 __attribute__((ext_vector_type(4)));

static __device__ __forceinline__ float sigmoidf_(float x) { return 1.0f / (1.0f + expf(-x)); }

// ---------------- CSR build ----------------
__global__ void k_deg(const int* __restrict__ ei, const float* __restrict__ ew,
                      unsigned long long* __restrict__ dc) {
  int e = blockIdx.x * blockDim.x + threadIdx.x;
  if (e >= Ee) return;
  int d = ei[Ee + e];
  unsigned long long pk = (1ULL << 42) + (unsigned long long)(ew[e] * 2097152.0f + 0.5f);
  atomicAdd(&dc[d], pk);
}

__global__ void k_dis(const unsigned long long* __restrict__ dc,
                      float* __restrict__ dis, int* __restrict__ cnt) {
  int i = blockIdx.x * blockDim.x + threadIdx.x;
  if (i >= Nn) return;
  unsigned long long v = dc[i];
  cnt[i] = (int)(v >> 42);
  float deg = (float)(v & ((1ULL << 42) - 1)) * (1.0f / 2097152.0f);
  dis[i] = 1.0f / sqrtf(deg + 1.0f);
}

// ---- multi-block exclusive scan of cnt[Nn] -> rp/cur ----
__global__ __launch_bounds__(256) void k_scan1(const int* __restrict__ cnt,
                                               int* __restrict__ bsum) {
  __shared__ int ss[256];
  int b = blockIdx.x, t = threadIdx.x;
  int base = b * 512 + t * 2;
  int s = 0;
  if (base < Nn) s += cnt[base];
  if (base + 1 < Nn) s += cnt[base + 1];
  ss[t] = s;
  __syncthreads();
  for (int off = 128; off > 0; off >>= 1) {
    if (t < off) ss[t] += ss[t + off];
    __syncthreads();
  }
  if (t == 0) bsum[b] = ss[0];
}

__global__ __launch_bounds__(128) void k_scan2(const int* __restrict__ bsum,
                                               int* __restrict__ boff) {
  __shared__ int ss[128];
  int t = threadIdx.x;
  int v = (t < SCAN_NB) ? bsum[t] : 0;
  ss[t] = v;
  __syncthreads();
  for (int off = 1; off < 128; off <<= 1) {
    int u = (t >= off) ? ss[t - off] : 0;
    __syncthreads();
    ss[t] += u;
    __syncthreads();
  }
  if (t < SCAN_NB) boff[t] = ss[t] - v;  // exclusive
}

__global__ __launch_bounds__(256) void k_scan3(const int* __restrict__ cnt,
                                               const int* __restrict__ boff,
                                               int* __restrict__ rp, int* __restrict__ cur) {
  __shared__ int ss[256];
  int b = blockIdx.x, t = threadIdx.x;
  int base = b * 512 + t * 2;
  int c0 = (base < Nn) ? cnt[base] : 0;
  int c1 = (base + 1 < Nn) ? cnt[base + 1] : 0;
  int s = c0 + c1;
  ss[t] = s;
  __syncthreads();
  for (int off = 1; off < 256; off <<= 1) {
    int u = (t >= off) ? ss[t - off] : 0;
    __syncthreads();
    ss[t] += u;
    __syncthreads();
  }
  int run = boff[b] + ss[t] - s;
  if (base < Nn) { rp[base] = run; cur[base] = run; }
  if (base + 1 < Nn) { rp[base + 1] = run + c0; cur[base + 1] = run + c0; }
  if (b == 0 && t == 0) rp[Nn] = Ee;
}

// edge2[pos] = {src, normalized fp32 weight}: ONE scattered 8-B store per edge
__global__ void k_scatter(const int* __restrict__ ei, const float* __restrict__ ew,
                          const float* __restrict__ dis, int* __restrict__ cur,
                          int2* __restrict__ edge2) {
  int e = blockIdx.x * blockDim.x + threadIdx.x;
  if (e >= Ee) return;
  int s = ei[e];
  int d = ei[Ee + e];
  float w = ew[e] * dis[s] * dis[d];
  int pos = atomicAdd(&cur[d], 1);
  edge2[pos] = make_int2(s, __float_as_int(w));
}

// edge4[e] = u16 src | fp16 w << 16 (sequential read/write; no second scatter stream)
__global__ void k_pack(const int2* __restrict__ edge2, unsigned* __restrict__ edge4) {
  int e = blockIdx.x * blockDim.x + threadIdx.x;
  if (e >= Ee) return;
  int2 v = edge2[e];
  __half wh = __float2half(__int_as_float(v.y));
  edge4[e] = (unsigned)(v.x & 0xFFFF) | ((unsigned)__half_as_ushort(wh) << 16);
}

// ---------------- x fp32 -> fp16 (once) ----------------
__global__ void k_cvt_x(const float* __restrict__ x, __half* __restrict__ x16) {
  size_t idx = (size_t)blockIdx.x * blockDim.x + threadIdx.x;
  const size_t total = (size_t)Nn * Ff * Tt;
  if (idx < total) x16[idx] = __float2half(x[idx]);
}

// ---------------- weight fragments for MFMA (once) ----------------
__global__ void k_wfrag(const float* __restrict__ Wz, const float* __restrict__ Wr,
                        const float* __restrict__ Wh, __half* __restrict__ frag) {
  int t = blockIdx.x * 256 + threadIdx.x;
  if (t >= 12 * 3 * 64) return;
  int s = t / 192, rem = t % 192, ks = rem / 64, lane = rem % 64;
  int q = lane >> 4, nl = lane & 15;
  const float* W = (s < 4) ? Wz : (s < 8) ? Wr : Wh;
  int n0 = (s & 3) * 16;
  __half tmp[8];
#pragma unroll
  for (int j = 0; j < 8; j++) {
    int k = ks * 32 + q * 8 + j;
    float v = (k < Cc) ? W[k * Hh + n0 + nl] : 0.f;
    tmp[j] = __float2half(v);
  }
  *(uint4*)(frag + ((size_t)(s * 3 + ks) * 64 + lane) * 8) = *(uint4*)tmp;
}

__global__ void k_wfrag_a(const float* __restrict__ Wa, __half* __restrict__ fragA) {
  int t = blockIdx.x * 256 + threadIdx.x;
  if (t >= 8 * 64) return;
  int s = t >> 6, lane = t & 63;
  int tile = s >> 1, ks = s & 1;
  int q = lane >> 4, m = lane & 15;
  __half tmp[8];
#pragma unroll
  for (int j = 0; j < 8; j++) {
    int k = ks * 32 + q * 8 + j;
    tmp[j] = __float2half(Wa[k * Hh + tile * 16 + m]);
  }
  *(uint4*)(fragA + ((size_t)t) * 8) = *(uint4*)tmp;
}

// ---------------- Px16[t][i][f] = (A_hat @ x): wave per node, 48 lanes x 8B per edge ----------------
// Junk odd-slot gathers redirected to row i (hot) instead of next node's random src.
__global__ __launch_bounds__(256) void k_agg_px(
    const float* __restrict__ x, const __half* __restrict__ x16, __half* __restrict__ Px16,
    const int* __restrict__ rp, const int2* __restrict__ edge2,
    const float* __restrict__ dis) {
  int i = blockIdx.x * 4 + (threadIdx.x >> 6);
  if (i >= Nn) return;
  int lane = threadIdx.x & 63;
  const int R = Ff * Tt;  // 192
  const bool act = lane < 48;
  float d = dis[i], sn = d * d;
  float a0 = 0.f, a1 = 0.f, a2 = 0.f, a3 = 0.f;
  if (act) {
    float4 sv = *(const float4*)(x + (size_t)i * R + 4 * lane);  // self, fp32 exact
    a0 = sn * sv.x; a1 = sn * sv.y; a2 = sn * sv.z; a3 = sn * sv.w;
  }
  int jb = rp[i], je = rp[i + 1];
  for (int j = jb; j < je; j += 2) {
    int jc1 = min(j + 1, Ee - 1);
    int2 e0 = edge2[j];
    int2 e1 = edge2[jc1];
    float w0 = __int_as_float(e0.y);
    bool v1 = (j + 1 < je);
    float w1 = v1 ? __int_as_float(e1.y) : 0.f;
    int s1 = v1 ? e1.x : i;  // cndmask: junk slot gathers own row (cached), not random
    if (act) {
      uint2 g0 = *(const uint2*)(x16 + (size_t)e0.x * R + 4 * lane);
      uint2 g1 = *(const uint2*)(x16 + (size_t)s1 * R + 4 * lane);
      float2 p01 = __half22float2(*reinterpret_cast<const __half2*>(&g0.x));
      float2 p23 = __half22float2(*reinterpret_cast<const __half2*>(&g0.y));
      float2 q01 = __half22float2(*reinterpret_cast<const __half2*>(&g1.x));
      float2 q23 = __half22float2(*reinterpret_cast<const __half2*>(&g1.y));
      a0 = fmaf(w0, p01.x, a0); a1 = fmaf(w0, p01.y, a1);
      a2 = fmaf(w0, p23.x, a2); a3 = fmaf(w0, p23.y, a3);
      a0 = fmaf(w1, q01.x, a0); a1 = fmaf(w1, q01.y, a1);
      a2 = fmaf(w1, q23.x, a2); a3 = fmaf(w1, q23.y, a3);
    }
  }
  if (act) {
#pragma unroll
    for (int k = 0; k < 4; k++) {
      int cch = 4 * lane + k;           // channel = f*T + t
      int f = cch / Tt, tt = cch % Tt;
      float val = (k == 0) ? a0 : (k == 1) ? a1 : (k == 2) ? a2 : a3;
      Px16[(size_t)tt * Nn * Ff + (size_t)i * Ff + f] = __float2half(val);
    }
  }
}

// ---- shared staging: Px rows (halves [0,16)) + zero tail (halves [80,104)) ----
static __device__ __forceinline__ void stage_px_zero(
    __half* sX16, const __half* __restrict__ Px16t, int i0, int tid) {
  if (tid < 32) {
    int n = tid >> 1, r = tid & 1;
    *(uint4*)(sX16 + n * 104 + r * 8) =
        *(const uint4*)(Px16t + (size_t)(i0 + n) * Ff + r * 8);
  } else if (tid < 80) {
    int p = tid - 32, n = p / 3, part = p % 3;
    *(uint4*)(sX16 + n * 104 + 80 + part * 8) = make_uint4(0u, 0u, 0u, 0u);
  }
}

// accumulate 8 fp16 channels (one uint4 gather) weighted by wt into a[8]
static __device__ __forceinline__ void acc8_(const uint4& gv, float wt, float* a) {
  float2 f0 = __half22float2(*reinterpret_cast<const __half2*>(&gv.x));
  float2 f1 = __half22float2(*reinterpret_cast<const __half2*>(&gv.y));
  float2 f2 = __half22float2(*reinterpret_cast<const __half2*>(&gv.z));
  float2 f3 = __half22float2(*reinterpret_cast<const __half2*>(&gv.w));
  a[0] = fmaf(wt, f0.x, a[0]); a[1] = fmaf(wt, f0.y, a[1]);
  a[2] = fmaf(wt, f1.x, a[2]); a[3] = fmaf(wt, f1.y, a[3]);
  a[4] = fmaf(wt, f2.x, a[4]); a[5] = fmaf(wt, f2.y, a[5]);
  a[6] = fmaf(wt, f3.x, a[6]); a[7] = fmaf(wt, f3.y, a[7]);
}

// ---- aggregation core: 8 lanes/edge x 16B, 8 edge slots, 4-deep (32 edges/iter) ----
// BRANCH-FREE junk elimination: out-of-range slots gather the dst's own row
// (L1-hot from the self term) via cndmask'd src, weight 0. Keeps R6's full MLP
// (single basic block, 8 VMEM hoisted) while removing ~45% random gather traffic
// that the clamp-to-next-node's-edges version issued (R8 lesson: branches broke MLP).
static __device__ __forceinline__ void agg_node_to_lds(
    __half* sX16, int n, int i, int lane,
    const __half* __restrict__ v, const int* __restrict__ rp,
    const unsigned* __restrict__ edge4, const float* __restrict__ dis) {
  int g = lane >> 3;   // edge slot 0..7
  int c = lane & 7;    // channel octet: halves [8c, 8c+8)
  float d = dis[i], sn = d * d;
  float a[8];
  {
    uint4 gv = *(const uint4*)(v + (size_t)i * Hh + 8 * c);  // self
    float ws = (g == 0) ? sn : 0.f;
    float2 f0 = __half22float2(*reinterpret_cast<const __half2*>(&gv.x));
    float2 f1 = __half22float2(*reinterpret_cast<const __half2*>(&gv.y));
    float2 f2 = __half22float2(*reinterpret_cast<const __half2*>(&gv.z));
    float2 f3 = __half22float2(*reinterpret_cast<const __half2*>(&gv.w));
    a[0] = ws * f0.x; a[1] = ws * f0.y; a[2] = ws * f1.x; a[3] = ws * f1.y;
    a[4] = ws * f2.x; a[5] = ws * f2.y; a[6] = ws * f3.x; a[7] = ws * f3.y;
  }
  int jb = rp[i], je = rp[i + 1];
  const unsigned si = (unsigned)i;
  for (int j0 = jb; j0 < je; j0 += 32) {
    int j1 = j0 + g, j2 = j0 + 8 + g, j3 = j0 + 16 + g, j4 = j0 + 24 + g;
    unsigned e1 = edge4[min(j1, Ee - 1)];
    unsigned e2 = edge4[min(j2, Ee - 1)];
    unsigned e3 = edge4[min(j3, Ee - 1)];
    unsigned e4 = edge4[min(j4, Ee - 1)];
    bool v1 = j1 < je, v2 = j2 < je, v3 = j3 < je, v4 = j4 < je;
    float w1 = v1 ? __half2float(__ushort_as_half((unsigned short)(e1 >> 16))) : 0.f;
    float w2 = v2 ? __half2float(__ushort_as_half((unsigned short)(e2 >> 16))) : 0.f;
    float w3 = v3 ? __half2float(__ushort_as_half((unsigned short)(e3 >> 16))) : 0.f;
    float w4 = v4 ? __half2float(__ushort_as_half((unsigned short)(e4 >> 16))) : 0.f;
    unsigned s1 = v1 ? (e1 & 0xFFFFu) : si;
    unsigned s2 = v2 ? (e2 & 0xFFFFu) : si;
    unsigned s3 = v3 ? (e3 & 0xFFFFu) : si;
    unsigned s4 = v4 ? (e4 & 0xFFFFu) : si;
    uint4 g1 = *(const uint4*)(v + (size_t)s1 * Hh + 8 * c);
    uint4 g2 = *(const uint4*)(v + (size_t)s2 * Hh + 8 * c);
    uint4 g3 = *(const uint4*)(v + (size_t)s3 * Hh + 8 * c);
    uint4 g4 = *(const uint4*)(v + (size_t)s4 * Hh + 8 * c);
    acc8_(g1, w1, a);
    acc8_(g2, w2, a);
    acc8_(g3, w3, a);
    acc8_(g4, w4, a);
  }
#pragma unroll
  for (int k2 = 0; k2 < 8; k2++) {
    a[k2] += __shfl_xor(a[k2], 8, 64);
    a[k2] += __shfl_xor(a[k2], 16, 64);
    a[k2] += __shfl_xor(a[k2], 32, 64);
  }
  if (g == 0) {
    __half2 h0 = __floats2half2_rn(a[0], a[1]);
    __half2 h1 = __floats2half2_rn(a[2], a[3]);
    __half2 h2 = __floats2half2_rn(a[4], a[5]);
    __half2 h3 = __floats2half2_rn(a[6], a[7]);
    uint4 st;
    st.x = *reinterpret_cast<unsigned int*>(&h0);
    st.y = *reinterpret_cast<unsigned int*>(&h1);
    st.z = *reinterpret_cast<unsigned int*>(&h2);
    st.w = *reinterpret_cast<unsigned int*>(&h3);
    *(uint4*)(sX16 + n * 104 + 16 + 8 * c) = st;  // 8 lanes x 16B contiguous
  }
}

// ---------------- FUSED agg(h16) + GEMM z/r ----------------
__global__ __launch_bounds__(256) void k_zr_f(
    const __half* __restrict__ Px16, const __half* __restrict__ h16,
    const __half* __restrict__ frag,
    const float* __restrict__ bz, const float* __restrict__ br,
    const int* __restrict__ rp, const unsigned* __restrict__ edge4,
    const float* __restrict__ dis,
    __half* __restrict__ zb16, __half* __restrict__ rh16, int tstep) {
  __shared__ __align__(16) __half sX16[16 * 104];
  const int tid = threadIdx.x;
  const int i0 = blockIdx.x * 16;  // Nn = 3125*16 exactly
  const int wv = tid >> 6, lane = tid & 63;
  stage_px_zero(sX16, Px16 + (size_t)tstep * Nn * Ff, i0, tid);
#pragma unroll
  for (int k = 0; k < 4; k++) {
    int n = wv * 4 + k;
    agg_node_to_lds(sX16, n, i0 + n, lane, h16, rp, edge4, dis);
  }
  __syncthreads();
  // b-fragments loaded AFTER the agg phase: fewer live VGPRs during gathers
  f16x8 bzf[3], brf[3];
#pragma unroll
  for (int ks = 0; ks < 3; ks++) {
    bzf[ks] = *(const f16x8*)(frag + ((size_t)(wv * 3 + ks) * 64 + lane) * 8);
    brf[ks] = *(const f16x8*)(frag + ((size_t)((4 + wv) * 3 + ks) * 64 + lane) * 8);
  }
  const int m = lane & 15, q = lane >> 4;
  f32x4 accz = {0.f, 0.f, 0.f, 0.f}, accr = {0.f, 0.f, 0.f, 0.f};
#pragma unroll
  for (int ks = 0; ks < 3; ks++) {
    f16x8 a = *(const f16x8*)(sX16 + m * 104 + ks * 32 + q * 8);
    accz = __builtin_amdgcn_mfma_f32_16x16x32_f16(a, bzf[ks], accz, 0, 0, 0);
    accr = __builtin_amdgcn_mfma_f32_16x16x32_f16(a, brf[ks], accr, 0, 0, 0);
  }
  const int o = wv * 16 + m;
  float bzo = bz[o], bro = br[o];
  const int nb = i0 + q * 4;
#pragma unroll
  for (int r = 0; r < 4; r++) {
    int node = nb + r;
    float zv = sigmoidf_(accz[r] + bzo);
    float rv = sigmoidf_(accr[r] + bro);
    float hv = __half2float(h16[(size_t)node * Hh + o]);
    zb16[(size_t)node * Hh + o] = __float2half(zv);
    rh16[(size_t)node * Hh + o] = __float2half(rv * hv);
  }
}

// ---------------- FUSED agg(rh16) + GEMM h + GRU update ----------------
__global__ __launch_bounds__(256) void k_h_f(
    const __half* __restrict__ Px16, const __half* __restrict__ rh16,
    const __half* __restrict__ zb16, float* __restrict__ h, __half* __restrict__ h16,
    __half* __restrict__ hs16, const __half* __restrict__ frag,
    const float* __restrict__ bh,
    const int* __restrict__ rp, const unsigned* __restrict__ edge4,
    const float* __restrict__ dis, int tstep) {
  __shared__ __align__(16) __half sX16[16 * 104];
  const int tid = threadIdx.x;
  const int i0 = blockIdx.x * 16;
  const int wv = tid >> 6, lane = tid & 63;
  stage_px_zero(sX16, Px16 + (size_t)tstep * Nn * Ff, i0, tid);
#pragma unroll
  for (int k = 0; k < 4; k++) {
    int n = wv * 4 + k;
    agg_node_to_lds(sX16, n, i0 + n, lane, rh16, rp, edge4, dis);
  }
  __syncthreads();
  f16x8 bf[3];
#pragma unroll
  for (int ks = 0; ks < 3; ks++)
    bf[ks] = *(const f16x8*)(frag + ((size_t)((8 + wv) * 3 + ks) * 64 + lane) * 8);
  const int m = lane & 15, q = lane >> 4;
  f32x4 acc = {0.f, 0.f, 0.f, 0.f};
#pragma unroll
  for (int ks = 0; ks < 3; ks++) {
    f16x8 a = *(const f16x8*)(sX16 + m * 104 + ks * 32 + q * 8);
    acc = __builtin_amdgcn_mfma_f32_16x16x32_f16(a, bf[ks], acc, 0, 0, 0);
  }
  const int o = wv * 16 + m;
  float bho = bh[o];
  const int nb = i0 + q * 4;
  __half* hst = hs16 + (size_t)tstep * Nn * Hh;
#pragma unroll
  for (int r = 0; r < 4; r++) {
    int node = nb + r;
    float hc = tanhf(acc[r] + bho);
    float zv = __half2float(zb16[(size_t)node * Hh + o]);
    float hv = h[(size_t)node * Hh + o];
    float hn = zv * hv + (1.0f - zv) * hc;
    h[(size_t)node * Hh + o] = hn;
    __half hh = __float2half(hn);
    h16[(size_t)node * Hh + o] = hh;
    hst[(size_t)node * Hh + o] = hh;
  }
}

// ---------------- attention + output via MFMA: wave per node ----------------
__global__ __launch_bounds__(256) void k_att(
    const __half* __restrict__ hs16, const __half* __restrict__ fragA,
    const float* __restrict__ ba, const float* __restrict__ cv,
    const float* __restrict__ Wfc, const float* __restrict__ bfc,
    float* __restrict__ out) {
  const int tid = threadIdx.x;
  const int wv = tid >> 6, lane = tid & 63;
  const int i = blockIdx.x * 4 + wv;
  if (i >= Nn) return;
  const int m = lane & 15, q = lane >> 4;

  f16x8 bf[4][2];
#pragma unroll
  for (int s = 0; s < 8; s++)
    bf[s >> 1][s & 1] = *(const f16x8*)(fragA + (size_t)(s * 64 + lane) * 8);

  const int tm = (m < Tt) ? m : (Tt - 1);
  const __half* hbase = hs16 + (size_t)tm * Nn * Hh + (size_t)i * Hh;
  f16x8 a0 = *(const f16x8*)(hbase + q * 8);
  f16x8 a1 = *(const f16x8*)(hbase + 32 + q * 8);

  f32x4 acc[4];
#pragma unroll
  for (int tile = 0; tile < 4; tile++) acc[tile] = f32x4{0.f, 0.f, 0.f, 0.f};
#pragma unroll
  for (int tile = 0; tile < 4; tile++) {
    acc[tile] = __builtin_amdgcn_mfma_f32_16x16x32_f16(a0, bf[tile][0], acc[tile], 0, 0, 0);
    acc[tile] = __builtin_amdgcn_mfma_f32_16x16x32_f16(a1, bf[tile][1], acc[tile], 0, 0, 0);
  }

  float ba_l[4], cv_l[4];
#pragma unroll
  for (int tile = 0; tile < 4; tile++) {
    ba_l[tile] = ba[tile * 16 + m];
    cv_l[tile] = cv[tile * 16 + m];
  }
  float ar[4];
#pragma unroll
  for (int r = 0; r < 4; r++) {
    float s = 0.f;
#pragma unroll
    for (int tile = 0; tile < 4; tile++)
      s += tanhf(acc[tile][r] + ba_l[tile]) * cv_l[tile];
    s += __shfl_xor(s, 1, 64);
    s += __shfl_xor(s, 2, 64);
    s += __shfl_xor(s, 4, 64);
    s += __shfl_xor(s, 8, 64);
    ar[r] = s;
  }
  float al[Tt];
#pragma unroll
  for (int t = 0; t < Tt; t++) al[t] = __shfl(ar[t & 3], (t >> 2) * 16, 64);
  float mx = al[0];
#pragma unroll
  for (int t = 1; t < Tt; t++) mx = fmaxf(mx, al[t]);
  float ssum = 0.f;
#pragma unroll
  for (int t = 0; t < Tt; t++) { al[t] = expf(al[t] - mx); ssum += al[t]; }
  float inv = 1.0f / ssum;
  float cx = 0.f;
#pragma unroll
  for (int t = 0; t < Tt; t++)
    cx = fmaf(al[t], __half2float(hs16[(size_t)t * Nn * Hh + (size_t)i * Hh + lane]), cx);
  float p = cx * inv * Wfc[lane];
#pragma unroll
  for (int off = 32; off >= 1; off >>= 1) p += __shfl_xor(p, off, 64);
  if (lane == 0) out[i] = p + bfc[0];
}

extern "C" void kernel_launch(void* const* d_in, const int* in_sizes, int n_in,
                              void* d_out, int out_size, void* d_ws, size_t ws_size,
                              hipStream_t stream) {
  const float* x   = (const float*)d_in[0];
  const int* ei    = (const int*)d_in[1];
  const float* ew  = (const float*)d_in[2];
  const float* Wz  = (const float*)d_in[3];
  const float* bz  = (const float*)d_in[4];
  const float* Wr  = (const float*)d_in[5];
  const float* br  = (const float*)d_in[6];
  const float* Wh  = (const float*)d_in[7];
  const float* bh  = (const float*)d_in[8];
  const float* Wa  = (const float*)d_in[9];
  const float* ba  = (const float*)d_in[10];
  const float* cv  = (const float*)d_in[11];
  const float* Wfc = (const float*)d_in[12];
  const float* bfc = (const float*)d_in[13];
  float* out = (float*)d_out;

  char* w = (char*)d_ws;
  auto alloc = [&](size_t bytes) {
    char* p = w;
    w += (bytes + 255) & ~(size_t)255;
    return p;
  };
  unsigned long long* dc = (unsigned long long*)alloc((size_t)Nn * 8);
  float* dis = (float*)alloc((size_t)Nn * 4);
  int* cnt   = (int*)alloc((size_t)Nn * 4);
  int* rp    = (int*)alloc((size_t)(Nn + 1) * 4);
  int* cur   = (int*)alloc((size_t)Nn * 4);
  int* bsum  = (int*)alloc((size_t)SCAN_NB * 4);
  int* boff  = (int*)alloc((size_t)SCAN_NB * 4);
  int2* edge2 = (int2*)alloc((size_t)Ee * 8);
  unsigned* edge4 = (unsigned*)alloc((size_t)Ee * 4);
  __half* x16  = (__half*)alloc((size_t)Nn * Ff * Tt * 2);
  __half* Px16 = (__half*)alloc((size_t)Tt * Nn * Ff * 2);
  float* h     = (float*)alloc((size_t)Nn * Hh * 4);
  __half* h16  = (__half*)alloc((size_t)Nn * Hh * 2);
  __half* rh16 = (__half*)alloc((size_t)Nn * Hh * 2);
  __half* zb16 = (__half*)alloc((size_t)Nn * Hh * 2);
  __half* hs16 = (__half*)alloc((size_t)Tt * Nn * Hh * 2);  // 76.8 MB history
  __half* wfrag = (__half*)alloc((size_t)12 * 3 * 64 * 8 * 2);
  __half* wfragA = (__half*)alloc((size_t)8 * 64 * 8 * 2);

  hipMemsetAsync(dc, 0, (size_t)Nn * 8, stream);
  hipMemsetAsync(h, 0, (size_t)Nn * Hh * 4, stream);
  hipMemsetAsync(h16, 0, (size_t)Nn * Hh * 2, stream);  // fp16 zero == 0x0000

  k_deg<<<(Ee + 255) / 256, 256, 0, stream>>>(ei, ew, dc);
  k_dis<<<(Nn + 255) / 256, 256, 0, stream>>>(dc, dis, cnt);
  k_scan1<<<SCAN_NB, 256, 0, stream>>>(cnt, bsum);
  k_scan2<<<1, 128, 0, stream>>>(bsum, boff);
  k_scan3<<<SCAN_NB, 256, 0, stream>>>(cnt, boff, rp, cur);
  k_scatter<<<(Ee + 255) / 256, 256, 0, stream>>>(ei, ew, dis, cur, edge2);
  k_pack<<<(Ee + 255) / 256, 256, 0, stream>>>(edge2, edge4);
  {
    const size_t total = (size_t)Nn * Ff * Tt;
    k_cvt_x<<<(int)((total + 255) / 256), 256, 0, stream>>>(x, x16);
  }
  k_wfrag<<<9, 256, 0, stream>>>(Wz, Wr, Wh, wfrag);
  k_wfrag_a<<<2, 256, 0, stream>>>(Wa, wfragA);
  k_agg_px<<<(Nn + 3) / 4, 256, 0, stream>>>(x, x16, Px16, rp, edge2, dis);

  const int gGemm = Nn / 16;  // 3125 blocks, 16 nodes each (exact)
  const int gNode = (Nn + 3) / 4;
  for (int t = 0; t < Tt; t++) {
    k_zr_f<<<gGemm, 256, 0, stream>>>(Px16, h16, wfrag, bz, br, rp, edge4, dis,
                                      zb16, rh16, t);
    k_h_f<<<gGemm, 256, 0, stream>>>(Px16, rh16, zb16, h, h16, hs16, wfrag, bh,
                                     rp, edge4, dis, t);
  }
  k_att<<<gNode, 256, 0, stream>>>(hs16, wfragA, ba, cv, Wfc, bfc, out);
}

// Round 10
// 1319.736 us; speedup vs baseline: 1.2233x; 1.0053x over previous
//
#include <hip/hip_runtime.h>
#include <hip/hip_fp16.h>
#include <math.h>

#define Nn 50000
#define Ff 16
#define Tt 12
#define Hh 64
#define Ee 1600000
#define Cc 80  // F + H

#define SCAN_NB 98  // ceil(50000 / 512)

typedef _Float16 f16x8 __attribute__((ext_vector_type(8)));
typedef float f32x4 __attribute__((ext_vector_type(4)));

static __device__ __forceinline__ float sigmoidf_(float x) { return 1.0f / (1.0f + expf(-x)); }

// ---------------- CSR build ----------------
__global__ void k_deg(const int* __restrict__ ei, const float* __restrict__ ew,
                      unsigned long long* __restrict__ dc) {
  int e = blockIdx.x * blockDim.x + threadIdx.x;
  if (e >= Ee) return;
  int d = ei[Ee + e];
  unsigned long long pk = (1ULL << 42) + (unsigned long long)(ew[e] * 2097152.0f + 0.5f);
  atomicAdd(&dc[d], pk);
}

__global__ void k_dis(const unsigned long long* __restrict__ dc,
                      float* __restrict__ dis, int* __restrict__ cnt) {
  int i = blockIdx.x * blockDim.x + threadIdx.x;
  if (i >= Nn) return;
  unsigned long long v = dc[i];
  cnt[i] = (int)(v >> 42);
  float deg = (float)(v & ((1ULL << 42) - 1)) * (1.0f / 2097152.0f);
  dis[i] = 1.0f / sqrtf(deg + 1.0f);
}

// ---- multi-block exclusive scan of cnt[Nn] -> rp/cur ----
__global__ __launch_bounds__(256) void k_scan1(const int* __restrict__ cnt,
                                               int* __restrict__ bsum) {
  __shared__ int ss[256];
  int b = blockIdx.x, t = threadIdx.x;
  int base = b * 512 + t * 2;
  int s = 0;
  if (base < Nn) s += cnt[base];
  if (base + 1 < Nn) s += cnt[base + 1];
  ss[t] = s;
  __syncthreads();
  for (int off = 128; off > 0; off >>= 1) {
    if (t < off) ss[t] += ss[t + off];
    __syncthreads();
  }
  if (t == 0) bsum[b] = ss[0];
}

__global__ __launch_bounds__(128) void k_scan2(const int* __restrict__ bsum,
                                               int* __restrict__ boff) {
  __shared__ int ss[128];
  int t = threadIdx.x;
  int v = (t < SCAN_NB) ? bsum[t] : 0;
  ss[t] = v;
  __syncthreads();
  for (int off = 1; off < 128; off <<= 1) {
    int u = (t >= off) ? ss[t - off] : 0;
    __syncthreads();
    ss[t] += u;
    __syncthreads();
  }
  if (t < SCAN_NB) boff[t] = ss[t] - v;  // exclusive
}

__global__ __launch_bounds__(256) void k_scan3(const int* __restrict__ cnt,
                                               const int* __restrict__ boff,
                                               int* __restrict__ rp, int* __restrict__ cur) {
  __shared__ int ss[256];
  int b = blockIdx.x, t = threadIdx.x;
  int base = b * 512 + t * 2;
  int c0 = (base < Nn) ? cnt[base] : 0;
  int c1 = (base + 1 < Nn) ? cnt[base + 1] : 0;
  int s = c0 + c1;
  ss[t] = s;
  __syncthreads();
  for (int off = 1; off < 256; off <<= 1) {
    int u = (t >= off) ? ss[t - off] : 0;
    __syncthreads();
    ss[t] += u;
    __syncthreads();
  }
  int run = boff[b] + ss[t] - s;
  if (base < Nn) { rp[base] = run; cur[base] = run; }
  if (base + 1 < Nn) { rp[base + 1] = run + c0; cur[base + 1] = run + c0; }
  if (b == 0 && t == 0) rp[Nn] = Ee;
}

// edge4[pos] = u16 src | fp16 w << 16: ONE scattered 4-B store per edge.
// (fp32 weights dropped: Px is stored fp16 downstream anyway, and the 8-B edge2
//  stream + k_pack cost more than the precision buys.)
__global__ void k_scatter(const int* __restrict__ ei, const float* __restrict__ ew,
                          const float* __restrict__ dis, int* __restrict__ cur,
                          unsigned* __restrict__ edge4) {
  int e = blockIdx.x * blockDim.x + threadIdx.x;
  if (e >= Ee) return;
  int s = ei[e];
  int d = ei[Ee + e];
  float w = ew[e] * dis[s] * dis[d];
  int pos = atomicAdd(&cur[d], 1);
  __half wh = __float2half(w);
  edge4[pos] = (unsigned)(s & 0xFFFF) | ((unsigned)__half_as_ushort(wh) << 16);
}

// ---------------- x fp32 -> fp16 (once) ----------------
__global__ void k_cvt_x(const float* __restrict__ x, __half* __restrict__ x16) {
  size_t idx = (size_t)blockIdx.x * blockDim.x + threadIdx.x;
  const size_t total = (size_t)Nn * Ff * Tt;
  if (idx < total) x16[idx] = __float2half(x[idx]);
}

// ---------------- weight fragments for MFMA (once) ----------------
__global__ void k_wfrag(const float* __restrict__ Wz, const float* __restrict__ Wr,
                        const float* __restrict__ Wh, __half* __restrict__ frag) {
  int t = blockIdx.x * 256 + threadIdx.x;
  if (t >= 12 * 3 * 64) return;
  int s = t / 192, rem = t % 192, ks = rem / 64, lane = rem % 64;
  int q = lane >> 4, nl = lane & 15;
  const float* W = (s < 4) ? Wz : (s < 8) ? Wr : Wh;
  int n0 = (s & 3) * 16;
  __half tmp[8];
#pragma unroll
  for (int j = 0; j < 8; j++) {
    int k = ks * 32 + q * 8 + j;
    float v = (k < Cc) ? W[k * Hh + n0 + nl] : 0.f;
    tmp[j] = __float2half(v);
  }
  *(uint4*)(frag + ((size_t)(s * 3 + ks) * 64 + lane) * 8) = *(uint4*)tmp;
}

__global__ void k_wfrag_a(const float* __restrict__ Wa, __half* __restrict__ fragA) {
  int t = blockIdx.x * 256 + threadIdx.x;
  if (t >= 8 * 64) return;
  int s = t >> 6, lane = t & 63;
  int tile = s >> 1, ks = s & 1;
  int q = lane >> 4, m = lane & 15;
  __half tmp[8];
#pragma unroll
  for (int j = 0; j < 8; j++) {
    int k = ks * 32 + q * 8 + j;
    tmp[j] = __float2half(Wa[k * Hh + tile * 16 + m]);
  }
  *(uint4*)(fragA + ((size_t)t) * 8) = *(uint4*)tmp;
}

// ---------------- Px16[t][i][f] = (A_hat @ x): wave per node, 48 lanes x 8B per edge ----------------
// edge4 stream (4 B/edge); junk odd-slot gathers redirected to row i (hot).
__global__ __launch_bounds__(256) void k_agg_px(
    const float* __restrict__ x, const __half* __restrict__ x16, __half* __restrict__ Px16,
    const int* __restrict__ rp, const unsigned* __restrict__ edge4,
    const float* __restrict__ dis) {
  int i = blockIdx.x * 4 + (threadIdx.x >> 6);
  if (i >= Nn) return;
  int lane = threadIdx.x & 63;
  const int R = Ff * Tt;  // 192
  const bool act = lane < 48;
  float d = dis[i], sn = d * d;
  float a0 = 0.f, a1 = 0.f, a2 = 0.f, a3 = 0.f;
  if (act) {
    float4 sv = *(const float4*)(x + (size_t)i * R + 4 * lane);  // self, fp32 exact
    a0 = sn * sv.x; a1 = sn * sv.y; a2 = sn * sv.z; a3 = sn * sv.w;
  }
  int jb = rp[i], je = rp[i + 1];
  const unsigned si = (unsigned)i;
  for (int j = jb; j < je; j += 2) {
    unsigned e0 = edge4[j];
    unsigned e1 = edge4[min(j + 1, Ee - 1)];
    float w0 = __half2float(__ushort_as_half((unsigned short)(e0 >> 16)));
    bool v1 = (j + 1 < je);
    float w1 = v1 ? __half2float(__ushort_as_half((unsigned short)(e1 >> 16))) : 0.f;
    unsigned s0 = e0 & 0xFFFFu;
    unsigned s1 = v1 ? (e1 & 0xFFFFu) : si;  // cndmask: junk slot gathers own row
    if (act) {
      uint2 g0 = *(const uint2*)(x16 + (size_t)s0 * R + 4 * lane);
      uint2 g1 = *(const uint2*)(x16 + (size_t)s1 * R + 4 * lane);
      float2 p01 = __half22float2(*reinterpret_cast<const __half2*>(&g0.x));
      float2 p23 = __half22float2(*reinterpret_cast<const __half2*>(&g0.y));
      float2 q01 = __half22float2(*reinterpret_cast<const __half2*>(&g1.x));
      float2 q23 = __half22float2(*reinterpret_cast<const __half2*>(&g1.y));
      a0 = fmaf(w0, p01.x, a0); a1 = fmaf(w0, p01.y, a1);
      a2 = fmaf(w0, p23.x, a2); a3 = fmaf(w0, p23.y, a3);
      a0 = fmaf(w1, q01.x, a0); a1 = fmaf(w1, q01.y, a1);
      a2 = fmaf(w1, q23.x, a2); a3 = fmaf(w1, q23.y, a3);
    }
  }
  if (act) {
#pragma unroll
    for (int k = 0; k < 4; k++) {
      int cch = 4 * lane + k;           // channel = f*T + t
      int f = cch / Tt, tt = cch % Tt;
      float val = (k == 0) ? a0 : (k == 1) ? a1 : (k == 2) ? a2 : a3;
      Px16[(size_t)tt * Nn * Ff + (size_t)i * Ff + f] = __float2half(val);
    }
  }
}

// ---- shared staging: Px rows (halves [0,16)) + zero tail (halves [80,104)) ----
static __device__ __forceinline__ void stage_px_zero(
    __half* sX16, const __half* __restrict__ Px16t, int i0, int tid) {
  if (tid < 32) {
    int n = tid >> 1, r = tid & 1;
    *(uint4*)(sX16 + n * 104 + r * 8) =
        *(const uint4*)(Px16t + (size_t)(i0 + n) * Ff + r * 8);
  } else if (tid < 80) {
    int p = tid - 32, n = p / 3, part = p % 3;
    *(uint4*)(sX16 + n * 104 + 80 + part * 8) = make_uint4(0u, 0u, 0u, 0u);
  }
}

// accumulate 8 fp16 channels (one uint4 gather) weighted by wt into a[8]
static __device__ __forceinline__ void acc8_(const uint4& gv, float wt, float* a) {
  float2 f0 = __half22float2(*reinterpret_cast<const __half2*>(&gv.x));
  float2 f1 = __half22float2(*reinterpret_cast<const __half2*>(&gv.y));
  float2 f2 = __half22float2(*reinterpret_cast<const __half2*>(&gv.z));
  float2 f3 = __half22float2(*reinterpret_cast<const __half2*>(&gv.w));
  a[0] = fmaf(wt, f0.x, a[0]); a[1] = fmaf(wt, f0.y, a[1]);
  a[2] = fmaf(wt, f1.x, a[2]); a[3] = fmaf(wt, f1.y, a[3]);
  a[4] = fmaf(wt, f2.x, a[4]); a[5] = fmaf(wt, f2.y, a[5]);
  a[6] = fmaf(wt, f3.x, a[6]); a[7] = fmaf(wt, f3.y, a[7]);
}

// ---- aggregation core: 8 lanes/edge x 16B, 8 edge slots, 4-deep (32 edges/iter) ----
// BRANCH-FREE junk elimination (R9, verified): out-of-range slots gather the dst's
// own row (L1-hot) via cndmask'd src, weight 0. Single basic block keeps MLP.
static __device__ __forceinline__ void agg_node_to_lds(
    __half* sX16, int n, int i, int lane,
    const __half* __restrict__ v, const int* __restrict__ rp,
    const unsigned* __restrict__ edge4, const float* __restrict__ dis) {
  int g = lane >> 3;   // edge slot 0..7
  int c = lane & 7;    // channel octet: halves [8c, 8c+8)
  float d = dis[i], sn = d * d;
  float a[8];
  {
    uint4 gv = *(const uint4*)(v + (size_t)i * Hh + 8 * c);  // self
    float ws = (g == 0) ? sn : 0.f;
    float2 f0 = __half22float2(*reinterpret_cast<const __half2*>(&gv.x));
    float2 f1 = __half22float2(*reinterpret_cast<const __half2*>(&gv.y));
    float2 f2 = __half22float2(*reinterpret_cast<const __half2*>(&gv.z));
    float2 f3 = __half22float2(*reinterpret_cast<const __half2*>(&gv.w));
    a[0] = ws * f0.x; a[1] = ws * f0.y; a[2] = ws * f1.x; a[3] = ws * f1.y;
    a[4] = ws * f2.x; a[5] = ws * f2.y; a[6] = ws * f3.x; a[7] = ws * f3.y;
  }
  int jb = rp[i], je = rp[i + 1];
  const unsigned si = (unsigned)i;
  for (int j0 = jb; j0 < je; j0 += 32) {
    int j1 = j0 + g, j2 = j0 + 8 + g, j3 = j0 + 16 + g, j4 = j0 + 24 + g;
    unsigned e1 = edge4[min(j1, Ee - 1)];
    unsigned e2 = edge4[min(j2, Ee - 1)];
    unsigned e3 = edge4[min(j3, Ee - 1)];
    unsigned e4 = edge4[min(j4, Ee - 1)];
    bool v1 = j1 < je, v2 = j2 < je, v3 = j3 < je, v4 = j4 < je;
    float w1 = v1 ? __half2float(__ushort_as_half((unsigned short)(e1 >> 16))) : 0.f;
    float w2 = v2 ? __half2float(__ushort_as_half((unsigned short)(e2 >> 16))) : 0.f;
    float w3 = v3 ? __half2float(__ushort_as_half((unsigned short)(e3 >> 16))) : 0.f;
    float w4 = v4 ? __half2float(__ushort_as_half((unsigned short)(e4 >> 16))) : 0.f;
    unsigned s1 = v1 ? (e1 & 0xFFFFu) : si;
    unsigned s2 = v2 ? (e2 & 0xFFFFu) : si;
    unsigned s3 = v3 ? (e3 & 0xFFFFu) : si;
    unsigned s4 = v4 ? (e4 & 0xFFFFu) : si;
    uint4 g1 = *(const uint4*)(v + (size_t)s1 * Hh + 8 * c);
    uint4 g2 = *(const uint4*)(v + (size_t)s2 * Hh + 8 * c);
    uint4 g3 = *(const uint4*)(v + (size_t)s3 * Hh + 8 * c);
    uint4 g4 = *(const uint4*)(v + (size_t)s4 * Hh + 8 * c);
    acc8_(g1, w1, a);
    acc8_(g2, w2, a);
    acc8_(g3, w3, a);
    acc8_(g4, w4, a);
  }
#pragma unroll
  for (int k2 = 0; k2 < 8; k2++) {
    a[k2] += __shfl_xor(a[k2], 8, 64);
    a[k2] += __shfl_xor(a[k2], 16, 64);
    a[k2] += __shfl_xor(a[k2], 32, 64);
  }
  if (g == 0) {
    __half2 h0 = __floats2half2_rn(a[0], a[1]);
    __half2 h1 = __floats2half2_rn(a[2], a[3]);
    __half2 h2 = __floats2half2_rn(a[4], a[5]);
    __half2 h3 = __floats2half2_rn(a[6], a[7]);
    uint4 st;
    st.x = *reinterpret_cast<unsigned int*>(&h0);
    st.y = *reinterpret_cast<unsigned int*>(&h1);
    st.z = *reinterpret_cast<unsigned int*>(&h2);
    st.w = *reinterpret_cast<unsigned int*>(&h3);
    *(uint4*)(sX16 + n * 104 + 16 + 8 * c) = st;  // 8 lanes x 16B contiguous
  }
}

// ---------------- FUSED agg(h16) + GEMM z/r ----------------
__global__ __launch_bounds__(256) void k_zr_f(
    const __half* __restrict__ Px16, const __half* __restrict__ h16,
    const __half* __restrict__ frag,
    const float* __restrict__ bz, const float* __restrict__ br,
    const int* __restrict__ rp, const unsigned* __restrict__ edge4,
    const float* __restrict__ dis,
    __half* __restrict__ zb16, __half* __restrict__ rh16, int tstep) {
  __shared__ __align__(16) __half sX16[16 * 104];
  const int tid = threadIdx.x;
  const int i0 = blockIdx.x * 16;  // Nn = 3125*16 exactly
  const int wv = tid >> 6, lane = tid & 63;
  stage_px_zero(sX16, Px16 + (size_t)tstep * Nn * Ff, i0, tid);
#pragma unroll
  for (int k = 0; k < 4; k++) {
    int n = wv * 4 + k;
    agg_node_to_lds(sX16, n, i0 + n, lane, h16, rp, edge4, dis);
  }
  __syncthreads();
  // b-fragments loaded AFTER the agg phase: fewer live VGPRs during gathers
  f16x8 bzf[3], brf[3];
#pragma unroll
  for (int ks = 0; ks < 3; ks++) {
    bzf[ks] = *(const f16x8*)(frag + ((size_t)(wv * 3 + ks) * 64 + lane) * 8);
    brf[ks] = *(const f16x8*)(frag + ((size_t)((4 + wv) * 3 + ks) * 64 + lane) * 8);
  }
  const int m = lane & 15, q = lane >> 4;
  f32x4 accz = {0.f, 0.f, 0.f, 0.f}, accr = {0.f, 0.f, 0.f, 0.f};
#pragma unroll
  for (int ks = 0; ks < 3; ks++) {
    f16x8 a = *(const f16x8*)(sX16 + m * 104 + ks * 32 + q * 8);
    accz = __builtin_amdgcn_mfma_f32_16x16x32_f16(a, bzf[ks], accz, 0, 0, 0);
    accr = __builtin_amdgcn_mfma_f32_16x16x32_f16(a, brf[ks], accr, 0, 0, 0);
  }
  const int o = wv * 16 + m;
  float bzo = bz[o], bro = br[o];
  const int nb = i0 + q * 4;
#pragma unroll
  for (int r = 0; r < 4; r++) {
    int node = nb + r;
    float zv = sigmoidf_(accz[r] + bzo);
    float rv = sigmoidf_(accr[r] + bro);
    float hv = __half2float(h16[(size_t)node * Hh + o]);
    zb16[(size_t)node * Hh + o] = __float2half(zv);
    rh16[(size_t)node * Hh + o] = __float2half(rv * hv);
  }
}

// ---------------- FUSED agg(rh16) + GEMM h + GRU update ----------------
// hs16 layout: [i][t][64] (node-major) so k_att reads each node's history as
// one contiguous 1536-B block instead of 16 scattered plane reads.
__global__ __launch_bounds__(256) void k_h_f(
    const __half* __restrict__ Px16, const __half* __restrict__ rh16,
    const __half* __restrict__ zb16, float* __restrict__ h, __half* __restrict__ h16,
    __half* __restrict__ hs16, const __half* __restrict__ frag,
    const float* __restrict__ bh,
    const int* __restrict__ rp, const unsigned* __restrict__ edge4,
    const float* __restrict__ dis, int tstep) {
  __shared__ __align__(16) __half sX16[16 * 104];
  const int tid = threadIdx.x;
  const int i0 = blockIdx.x * 16;
  const int wv = tid >> 6, lane = tid & 63;
  stage_px_zero(sX16, Px16 + (size_t)tstep * Nn * Ff, i0, tid);
#pragma unroll
  for (int k = 0; k < 4; k++) {
    int n = wv * 4 + k;
    agg_node_to_lds(sX16, n, i0 + n, lane, rh16, rp, edge4, dis);
  }
  __syncthreads();
  f16x8 bf[3];
#pragma unroll
  for (int ks = 0; ks < 3; ks++)
    bf[ks] = *(const f16x8*)(frag + ((size_t)((8 + wv) * 3 + ks) * 64 + lane) * 8);
  const int m = lane & 15, q = lane >> 4;
  f32x4 acc = {0.f, 0.f, 0.f, 0.f};
#pragma unroll
  for (int ks = 0; ks < 3; ks++) {
    f16x8 a = *(const f16x8*)(sX16 + m * 104 + ks * 32 + q * 8);
    acc = __builtin_amdgcn_mfma_f32_16x16x32_f16(a, bf[ks], acc, 0, 0, 0);
  }
  const int o = wv * 16 + m;
  float bho = bh[o];
  const int nb = i0 + q * 4;
#pragma unroll
  for (int r = 0; r < 4; r++) {
    int node = nb + r;
    float hc = tanhf(acc[r] + bho);
    float zv = __half2float(zb16[(size_t)node * Hh + o]);
    float hv = h[(size_t)node * Hh + o];
    float hn = zv * hv + (1.0f - zv) * hc;
    h[(size_t)node * Hh + o] = hn;
    __half hh = __float2half(hn);
    h16[(size_t)node * Hh + o] = hh;
    hs16[(size_t)node * (Tt * Hh) + tstep * Hh + o] = hh;  // node-major history
  }
}

// ---------------- attention + output via MFMA: wave per node ----------------
// hs16 node-major: A-frags stream the node's contiguous 1536-B history;
// context re-reads the same block (L1/L2-hot).
__global__ __launch_bounds__(256) void k_att(
    const __half* __restrict__ hs16, const __half* __restrict__ fragA,
    const float* __restrict__ ba, const float* __restrict__ cv,
    const float* __restrict__ Wfc, const float* __restrict__ bfc,
    float* __restrict__ out) {
  const int tid = threadIdx.x;
  const int wv = tid >> 6, lane = tid & 63;
  const int i = blockIdx.x * 4 + wv;
  if (i >= Nn) return;
  const int m = lane & 15, q = lane >> 4;

  f16x8 bf[4][2];
#pragma unroll
  for (int s = 0; s < 8; s++)
    bf[s >> 1][s & 1] = *(const f16x8*)(fragA + (size_t)(s * 64 + lane) * 8);

  const int tm = (m < Tt) ? m : (Tt - 1);
  const __half* hbase = hs16 + (size_t)i * (Tt * Hh) + tm * Hh;
  f16x8 a0 = *(const f16x8*)(hbase + q * 8);
  f16x8 a1 = *(const f16x8*)(hbase + 32 + q * 8);

  f32x4 acc[4];
#pragma unroll
  for (int tile = 0; tile < 4; tile++) acc[tile] = f32x4{0.f, 0.f, 0.f, 0.f};
#pragma unroll
  for (int tile = 0; tile < 4; tile++) {
    acc[tile] = __builtin_amdgcn_mfma_f32_16x16x32_f16(a0, bf[tile][0], acc[tile], 0, 0, 0);
    acc[tile] = __builtin_amdgcn_mfma_f32_16x16x32_f16(a1, bf[tile][1], acc[tile], 0, 0, 0);
  }

  float ba_l[4], cv_l[4];
#pragma unroll
  for (int tile = 0; tile < 4; tile++) {
    ba_l[tile] = ba[tile * 16 + m];
    cv_l[tile] = cv[tile * 16 + m];
  }
  float ar[4];
#pragma unroll
  for (int r = 0; r < 4; r++) {
    float s = 0.f;
#pragma unroll
    for (int tile = 0; tile < 4; tile++)
      s += tanhf(acc[tile][r] + ba_l[tile]) * cv_l[tile];
    s += __shfl_xor(s, 1, 64);
    s += __shfl_xor(s, 2, 64);
    s += __shfl_xor(s, 4, 64);
    s += __shfl_xor(s, 8, 64);
    ar[r] = s;
  }
  float al[Tt];
#pragma unroll
  for (int t = 0; t < Tt; t++) al[t] = __shfl(ar[t & 3], (t >> 2) * 16, 64);
  float mx = al[0];
#pragma unroll
  for (int t = 1; t < Tt; t++) mx = fmaxf(mx, al[t]);
  float ssum = 0.f;
#pragma unroll
  for (int t = 0; t < Tt; t++) { al[t] = expf(al[t] - mx); ssum += al[t]; }
  float inv = 1.0f / ssum;
  float cx = 0.f;
#pragma unroll
  for (int t = 0; t < Tt; t++)
    cx = fmaf(al[t], __half2float(hs16[(size_t)i * (Tt * Hh) + t * Hh + lane]), cx);
  float p = cx * inv * Wfc[lane];
#pragma unroll
  for (int off = 32; off >= 1; off >>= 1) p += __shfl_xor(p, off, 64);
  if (lane == 0) out[i] = p + bfc[0];
}

extern "C" void kernel_launch(void* const* d_in, const int* in_sizes, int n_in,
                              void* d_out, int out_size, void* d_ws, size_t ws_size,
                              hipStream_t stream) {
  const float* x   = (const float*)d_in[0];
  const int* ei    = (const int*)d_in[1];
  const float* ew  = (const float*)d_in[2];
  const float* Wz  = (const float*)d_in[3];
  const float* bz  = (const float*)d_in[4];
  const float* Wr  = (const float*)d_in[5];
  const float* br  = (const float*)d_in[6];
  const float* Wh  = (const float*)d_in[7];
  const float* bh  = (const float*)d_in[8];
  const float* Wa  = (const float*)d_in[9];
  const float* ba  = (const float*)d_in[10];
  const float* cv  = (const float*)d_in[11];
  const float* Wfc = (const float*)d_in[12];
  const float* bfc = (const float*)d_in[13];
  float* out = (float*)d_out;

  char* w = (char*)d_ws;
  auto alloc = [&](size_t bytes) {
    char* p = w;
    w += (bytes + 255) & ~(size_t)255;
    return p;
  };
  unsigned long long* dc = (unsigned long long*)alloc((size_t)Nn * 8);
  float* dis = (float*)alloc((size_t)Nn * 4);
  int* cnt   = (int*)alloc((size_t)Nn * 4);
  int* rp    = (int*)alloc((size_t)(Nn + 1) * 4);
  int* cur   = (int*)alloc((size_t)Nn * 4);
  int* bsum  = (int*)alloc((size_t)SCAN_NB * 4);
  int* boff  = (int*)alloc((size_t)SCAN_NB * 4);
  unsigned* edge4 = (unsigned*)alloc((size_t)Ee * 4);
  __half* x16  = (__half*)alloc((size_t)Nn * Ff * Tt * 2);
  __half* Px16 = (__half*)alloc((size_t)Tt * Nn * Ff * 2);
  float* h     = (float*)alloc((size_t)Nn * Hh * 4);
  __half* h16  = (__half*)alloc((size_t)Nn * Hh * 2);
  __half* rh16 = (__half*)alloc((size_t)Nn * Hh * 2);
  __half* zb16 = (__half*)alloc((size_t)Nn * Hh * 2);
  __half* hs16 = (__half*)alloc((size_t)Nn * Tt * Hh * 2);  // 76.8 MB, node-major
  __half* wfrag = (__half*)alloc((size_t)12 * 3 * 64 * 8 * 2);
  __half* wfragA = (__half*)alloc((size_t)8 * 64 * 8 * 2);

  hipMemsetAsync(dc, 0, (size_t)Nn * 8, stream);
  hipMemsetAsync(h, 0, (size_t)Nn * Hh * 4, stream);
  hipMemsetAsync(h16, 0, (size_t)Nn * Hh * 2, stream);  // fp16 zero == 0x0000

  k_deg<<<(Ee + 255) / 256, 256, 0, stream>>>(ei, ew, dc);
  k_dis<<<(Nn + 255) / 256, 256, 0, stream>>>(dc, dis, cnt);
  k_scan1<<<SCAN_NB, 256, 0, stream>>>(cnt, bsum);
  k_scan2<<<1, 128, 0, stream>>>(bsum, boff);
  k_scan3<<<SCAN_NB, 256, 0, stream>>>(cnt, boff, rp, cur);
  k_scatter<<<(Ee + 255) / 256, 256, 0, stream>>>(ei, ew, dis, cur, edge4);
  {
    const size_t total = (size_t)Nn * Ff * Tt;
    k_cvt_x<<<(int)((total + 255) / 256), 256, 0, stream>>>(x, x16);
  }
  k_wfrag<<<9, 256, 0, stream>>>(Wz, Wr, Wh, wfrag);
  k_wfrag_a<<<2, 256, 0, stream>>>(Wa, wfragA);
  k_agg_px<<<(Nn + 3) / 4, 256, 0, stream>>>(x, x16, Px16, rp, edge4, dis);

  const int gGemm = Nn / 16;  // 3125 blocks, 16 nodes each (exact)
  const int gNode = (Nn + 3) / 4;
  for (int t = 0; t < Tt; t++) {
    k_zr_f<<<gGemm, 256, 0, stream>>>(Px16, h16, wfrag, bz, br, rp, edge4, dis,
                                      zb16, rh16, t);
    k_h_f<<<gGemm, 256, 0, stream>>>(Px16, rh16, zb16, h, h16, hs16, wfrag, bh,
                                     rp, edge4, dis, t);
  }
  k_att<<<gNode, 256, 0, stream>>>(hs16, wfragA, ba, cv, Wfc, bfc, out);
}